// Round 7
// baseline (727.065 us; speedup 1.0000x reference)
//
#include <hip/hip_runtime.h>
#include <hip/hip_fp16.h>
#include <math.h>

#define NN 50000
#define NE 800000
#define TT 6
#define HID 48
#define NB 196   // (NN+255)/256

__device__ __forceinline__ float sigmoidf_(float x){ return 1.0f/(1.0f+__expf(-x)); }
__device__ __forceinline__ float tanhf_(float x){
  float xc = fminf(fmaxf(x,-15.f),15.f);
  float t = __expf(2.f*xc);
  return (t-1.f)/(t+1.f);
}
__device__ __forceinline__ unsigned f2bf(float x){
  unsigned u = __float_as_uint(x);
  return (u + 0x7fffu + ((u>>16)&1u)) >> 16;   // RNE to bf16
}
__device__ __forceinline__ unsigned pack2(float a, float b){
  return f2bf(a) | (f2bf(b)<<16);
}
__device__ __forceinline__ float bflo(unsigned u){ return __uint_as_float(u<<16); }
__device__ __forceinline__ float bfhi(unsigned u){ return __uint_as_float(u & 0xffff0000u); }
__device__ __forceinline__ unsigned f2h(float x){
  return (unsigned)__half_as_ushort(__float2half(x));   // RNE fp16
}
__device__ __forceinline__ float h2f(unsigned u){
  return __half2float(__ushort_as_half((unsigned short)(u & 0xffffu)));
}
__device__ __forceinline__ unsigned pack2h(float a, float b){   // RNE fp16 pair
  return f2h(a) | (f2h(b)<<16);
}

typedef __fp16 h2t __attribute__((ext_vector_type(2)));

__device__ __forceinline__ unsigned pkrtz(float a, float b){    // fast packed cvt (RTZ)
#if __has_builtin(__builtin_amdgcn_cvt_pkrtz)
  auto r = __builtin_amdgcn_cvt_pkrtz(a, b);
  return __builtin_bit_cast(unsigned, r);
#else
  return pack2h(a, b);
#endif
}
// acc += lo(a)*lo(b) + hi(a)*hi(b), fp32 accumulate
__device__ __forceinline__ float dot2f(unsigned a, unsigned b, float c){
#if __has_builtin(__builtin_amdgcn_fdot2)
  return __builtin_amdgcn_fdot2(__builtin_bit_cast(h2t, a), __builtin_bit_cast(h2t, b), c, false);
#else
  h2t av = __builtin_bit_cast(h2t, a), bv = __builtin_bit_cast(h2t, b);
  return c + (float)av[0]*(float)bv[0] + (float)av[1]*(float)bv[1];
#endif
}

struct U3 { unsigned x,y,z; };

// 256-thread inclusive block scan (4 waves of 64)
__device__ __forceinline__ int block_scan_incl(int x, int* wsum){
  int lane = threadIdx.x & 63, w = threadIdx.x >> 6;
  int v = x;
#pragma unroll
  for(int d=1; d<64; d<<=1){
    int u = __shfl_up(v, d, 64);
    if(lane >= d) v += u;
  }
  if(lane==63) wsum[w] = v;
  __syncthreads();
  int add = 0;
#pragma unroll
  for(int k=0;k<3;k++) if(w>k) add += wsum[k];
  return v + add;
}

// ---------------- setup: cnt/degf init + GRU weight repack (fp16 pairs along k) ----------------
// Wall [6 wv][24 k2][48 c] u32:
//   c<24  : h-side, row map: c<8 -> r (wv*8+c), c<16 -> z (48+wv*8+c-8), else n (96+wv*8+c-16)
//   c>=24 : x-side, same row map on (c-24), from Wih.
__global__ __launch_bounds__(256) void k_setup(int* cnt, float* degf,
                                               const float* __restrict__ Wih, const float* __restrict__ Whh,
                                               unsigned* Wall){
  int i = blockIdx.x*256+threadIdx.x;
  if(i<NN){ cnt[i]=0; degf[i]=0.f; }
  if(i < 6*24*48){
    int wv = i/1152, r = i%1152;
    int k2 = r/48, c = r%48;
    int cc = (c<24)? c : (c-24);
    int row = (cc<8) ? (wv*8 + cc) : (cc<16) ? (48 + wv*8 + cc-8) : (96 + wv*8 + cc-16);
    const float* Wsrc = (c<24)? Whh : Wih;
    Wall[i] = pack2h(Wsrc[row*48 + 2*k2], Wsrc[row*48 + 2*k2 + 1]);
  }
}

// per edge: rank within destination bucket + float degree accumulation (same cacheline region)
__global__ __launch_bounds__(256) void k_cnt(const int* __restrict__ ei, const float* __restrict__ ew,
                                             int* cnt, float* degf, int* pos){
  int e = blockIdx.x*256+threadIdx.x;
  if(e<NE){
    int c = ei[NE+e];
    pos[e] = atomicAdd(&cnt[c], 1);
    atomicAdd(&degf[c], ew[e]);
  }
}

// phase A: per-block sums of cnt; also finalize dis = rsqrt(1+degf) in place
__global__ __launch_bounds__(256) void k_partA(const int* __restrict__ cnt, int* bsum, float* dis){
  __shared__ int wsum[4];
  int i = blockIdx.x*256+threadIdx.x;
  int x = (i<NN)? cnt[i] : 0;
  if(i<NN) dis[i] = rsqrtf(1.f + dis[i]);   // dis buffer held degf
  int lane = threadIdx.x & 63, w = threadIdx.x >> 6;
  int v = x;
#pragma unroll
  for(int m=32;m>=1;m>>=1) v += __shfl_xor(v, m, 64);
  if(lane==0) wsum[w]=v;
  __syncthreads();
  if(threadIdx.x==0) bsum[blockIdx.x] = wsum[0]+wsum[1]+wsum[2]+wsum[3];
}

// phase B: exclusive scan of 196 block sums
__global__ __launch_bounds__(256) void k_midB(const int* __restrict__ bsum, int* bpre, int* offs){
  __shared__ int wsum[4];
  int t = threadIdx.x;
  int x = (t<NB)? bsum[t] : 0;
  int incl = block_scan_incl(x, wsum);
  if(t<NB) bpre[t] = incl - x;
  if(t==255) offs[NN] = incl;   // total
}

// phase C: per-block exclusive scan of cnt + bpre -> offs
__global__ __launch_bounds__(256) void k_offsC(const int* __restrict__ cnt, const int* __restrict__ bpre,
                                               int* offs){
  __shared__ int wsum[4];
  int i = blockIdx.x*256+threadIdx.x;
  int x = (i<NN)? cnt[i] : 0;
  int incl = block_scan_incl(x, wsum);
  if(i<NN) offs[i] = bpre[blockIdx.x] + incl - x;
}

// atomic-free scatter with normalization folded in: csr[offs[c]+pos[e]] = (row, dis[row]*ew)
__global__ __launch_bounds__(256) void k_scatter(const int* __restrict__ ei, const float* __restrict__ ew,
                                                 const int* __restrict__ offs, const int* __restrict__ pos,
                                                 const float* __restrict__ dis, int2* __restrict__ csr){
  int e = blockIdx.x*256+threadIdx.x;
  if(e<NE){
    int c = ei[NE+e];
    int r = ei[e];
    int2 v; v.x = r; v.y = __float_as_int(dis[r]*ew[e]);
    csr[offs[c]+pos[e]] = v;
  }
}

// ---------------- layer-0 matmul: wave = feature slice (uniform), lane = node ----------------
// A row per node = 144 words (576B): feature f at word offset f*3, bf16 [t6].
__global__ __launch_bounds__(256) void k_mm0(const float* __restrict__ X, const float* __restrict__ W,
                                             unsigned* __restrict__ A){
  int s = __builtin_amdgcn_readfirstlane(threadIdx.x>>6);   // 0..3, wave-uniform
  int n = blockIdx.x*64 + (threadIdx.x&63);
  if(n>=NN) return;
  const float* xb = X + (long long)n*64;
  const float* wb = W + 12*s;
  float acc[TT][12];
#pragma unroll
  for(int t=0;t<TT;t++)
#pragma unroll
    for(int j=0;j<12;j++) acc[t][j]=0.f;
#pragma unroll 2
  for(int k4=0;k4<16;k4++){
    float4 xv[TT];
#pragma unroll
    for(int t=0;t<TT;t++) xv[t] = *reinterpret_cast<const float4*>(xb + (long long)t*NN*64 + 4*k4);
#pragma unroll
    for(int q=0;q<4;q++){
      const float* wr = wb + (4*k4+q)*HID;
      float w[12];
#pragma unroll
      for(int j=0;j<12;j++) w[j]=wr[j];   // uniform addr -> s_load
#pragma unroll
      for(int t=0;t<TT;t++){
        float xs = (&xv[t].x)[q];
#pragma unroll
        for(int j=0;j<12;j++) acc[t][j] = fmaf(xs, w[j], acc[t][j]);
      }
    }
  }
  unsigned buf[36];
#pragma unroll
  for(int j=0;j<12;j++){
    buf[3*j  ]=pack2(acc[0][j],acc[1][j]);
    buf[3*j+1]=pack2(acc[2][j],acc[3][j]);
    buf[3*j+2]=pack2(acc[4][j],acc[5][j]);
  }
  uint4* o4 = reinterpret_cast<uint4*>(A + (long long)n*144 + 36*s);
#pragma unroll
  for(int q=0;q<9;q++) o4[q] = make_uint4(buf[4*q],buf[4*q+1],buf[4*q+2],buf[4*q+3]);
}

// ---------------- layer-1 matmul (K=48), input fp32 [n][t][48] ----------------
__global__ __launch_bounds__(256) void k_mm1(const float* __restrict__ X, const float* __restrict__ W,
                                             unsigned* __restrict__ A){
  int s = __builtin_amdgcn_readfirstlane(threadIdx.x>>6);
  int n = blockIdx.x*64 + (threadIdx.x&63);
  if(n>=NN) return;
  const float* xb = X + (long long)n*(TT*HID);
  const float* wb = W + 12*s;
  float acc[TT][12];
#pragma unroll
  for(int t=0;t<TT;t++)
#pragma unroll
    for(int j=0;j<12;j++) acc[t][j]=0.f;
#pragma unroll 2
  for(int k4=0;k4<12;k4++){
    float4 xv[TT];
#pragma unroll
    for(int t=0;t<TT;t++) xv[t] = *reinterpret_cast<const float4*>(xb + t*HID + 4*k4);
#pragma unroll
    for(int q=0;q<4;q++){
      const float* wr = wb + (4*k4+q)*HID;
      float w[12];
#pragma unroll
      for(int j=0;j<12;j++) w[j]=wr[j];
#pragma unroll
      for(int t=0;t<TT;t++){
        float xs = (&xv[t].x)[q];
#pragma unroll
        for(int j=0;j<12;j++) acc[t][j] = fmaf(xs, w[j], acc[t][j]);
      }
    }
  }
  unsigned buf[36];
#pragma unroll
  for(int j=0;j<12;j++){
    buf[3*j  ]=pack2(acc[0][j],acc[1][j]);
    buf[3*j+1]=pack2(acc[2][j],acc[3][j]);
    buf[3*j+2]=pack2(acc[4][j],acc[5][j]);
  }
  uint4* o4 = reinterpret_cast<uint4*>(A + (long long)n*144 + 36*s);
#pragma unroll
  for(int q=0;q<9;q++) o4[q] = make_uint4(buf[4*q],buf[4*q+1],buf[4*q+2],buf[4*q+3]);
}

// ---------------- CSR aggregation (bf16 gather, 8-deep MLP) + bias + LN + ReLU (+resid)
// edge norm stored = dis[r]*ew ; dis[c] factored: out = dn*(Σ nr*x_r + dn*x_c)
__global__ __launch_bounds__(256) void k_agg(const unsigned* __restrict__ A, const float* __restrict__ bias,
                                             const float* __restrict__ gain, const float* __restrict__ beta,
                                             const float* __restrict__ resid, float* __restrict__ out,
                                             const int* __restrict__ offs, const int2* __restrict__ csr,
                                             const float* __restrict__ dis){
  int wid = (blockIdx.x*256+threadIdx.x)>>6;
  int lane = threadIdx.x & 63;
  if(wid>=NN) return;
  const bool act = lane<HID;
  const int f = act? lane : (HID-1);
  float dn = dis[wid];
  float acc[TT];
  {
    U3 v = *reinterpret_cast<const U3*>(A + (long long)wid*144 + 3*f);
    acc[0]=dn*bflo(v.x); acc[1]=dn*bfhi(v.x);
    acc[2]=dn*bflo(v.y); acc[3]=dn*bfhi(v.y);
    acc[4]=dn*bflo(v.z); acc[5]=dn*bfhi(v.z);
  }
  int e0=offs[wid], e1=offs[wid+1];
  int e=e0;
  for(; e+7<e1; e+=8){                      // 8-deep: more loads in flight per wave
    int2 ii[8];
#pragma unroll
    for(int u=0;u<8;u++) ii[u]=csr[e+u];
    U3 dd[8];
#pragma unroll
    for(int u=0;u<8;u++) dd[u]=*reinterpret_cast<const U3*>(A + (long long)ii[u].x*144 + 3*f);
#pragma unroll
    for(int u=0;u<8;u++){
      float nr=__int_as_float(ii[u].y);
      acc[0]=fmaf(nr,bflo(dd[u].x),acc[0]); acc[1]=fmaf(nr,bfhi(dd[u].x),acc[1]);
      acc[2]=fmaf(nr,bflo(dd[u].y),acc[2]); acc[3]=fmaf(nr,bfhi(dd[u].y),acc[3]);
      acc[4]=fmaf(nr,bflo(dd[u].z),acc[4]); acc[5]=fmaf(nr,bfhi(dd[u].z),acc[5]);
    }
  }
  for(; e+3<e1; e+=4){
    int2 ii[4];
#pragma unroll
    for(int u=0;u<4;u++) ii[u]=csr[e+u];
    U3 dd[4];
#pragma unroll
    for(int u=0;u<4;u++) dd[u]=*reinterpret_cast<const U3*>(A + (long long)ii[u].x*144 + 3*f);
#pragma unroll
    for(int u=0;u<4;u++){
      float nr=__int_as_float(ii[u].y);
      acc[0]=fmaf(nr,bflo(dd[u].x),acc[0]); acc[1]=fmaf(nr,bfhi(dd[u].x),acc[1]);
      acc[2]=fmaf(nr,bflo(dd[u].y),acc[2]); acc[3]=fmaf(nr,bfhi(dd[u].y),acc[3]);
      acc[4]=fmaf(nr,bflo(dd[u].z),acc[4]); acc[5]=fmaf(nr,bfhi(dd[u].z),acc[5]);
    }
  }
  for(; e<e1; ++e){
    int2 i0=csr[e];
    U3 d0 = *reinterpret_cast<const U3*>(A + (long long)i0.x*144 + 3*f);
    float n0=__int_as_float(i0.y);
    acc[0]=fmaf(n0,bflo(d0.x),acc[0]); acc[1]=fmaf(n0,bfhi(d0.x),acc[1]);
    acc[2]=fmaf(n0,bflo(d0.y),acc[2]); acc[3]=fmaf(n0,bfhi(d0.y),acc[3]);
    acc[4]=fmaf(n0,bflo(d0.z),acc[4]); acc[5]=fmaf(n0,bfhi(d0.z),acc[5]);
  }
  float bb = bias[f], gg = gain[f], be = beta[f];
  const float rn = 1.0f/HID;
#pragma unroll
  for(int t=0;t<TT;t++){
    float val = fmaf(acc[t], dn, bb);    // final *dn fold
    float v = act? val : 0.f;
    float s = v, s2 = v*v;
#pragma unroll
    for(int m=32;m>=1;m>>=1){
      s  += __shfl_xor(s,  m, 64);
      s2 += __shfl_xor(s2, m, 64);
    }
    float mu  = s*rn;
    float var = fmaxf(s2*rn - mu*mu, 0.f);
    float y = (val-mu)*rsqrtf(var+1e-5f)*gg + be;
    y = fmaxf(y, 0.f);
    long long oidx = (long long)wid*(TT*HID) + t*HID + f;
    if(resid) y += resid[oidx];
    if(act) out[oidx] = y;
  }
}

// ---------------- fused GRU (x-side + h-side, fp16 dot2) + classifier [r5 proven shape] ----------
// block: 64 nodes, 384 threads = 6 waves. Wave wv owns 8 features, lane = node.
// x (all 6 steps) staged ONCE into LDS as fp16 pairs [t][k2][lane] (36 KB);
// h double-buffered fp16 [2][24][64] (12 KB). k-loop: ds_read_b32 x2 + ws[48] s_load
// + 48 dot2, unroll 2.
__global__ __launch_bounds__(384) void k_gruF2(const float* __restrict__ X,     // h2 [n][t][48]
                                               const unsigned* __restrict__ Wall, // [6][24][48] u32
                                               const float* __restrict__ bih, const float* __restrict__ bhh,
                                               const float* __restrict__ Wc1, const float* __restrict__ bc1,
                                               const float* __restrict__ Wc2, const float* __restrict__ bc2,
                                               float* __restrict__ out){
  __shared__ unsigned xall[TT*24*64];   // 36 KB
  __shared__ unsigned hb[2][24*64];     // 12 KB
  int tid = threadIdx.x;
  int wv = __builtin_amdgcn_readfirstlane(tid>>6);   // 0..5, uniform
  int lane = tid & 63;
  int f0 = wv*8;
  long long n = (long long)blockIdx.x*64 + lane;
  long long gn = (n<NN)? n : (NN-1);

  // stage x: wave wv stages timestep wv (12 float4 loads -> 24 packed writes)
  {
    const float* xb = X + gn*(TT*HID) + wv*HID;
#pragma unroll
    for(int q=0;q<12;q++){
      float4 v = *reinterpret_cast<const float4*>(xb + 4*q);
      xall[(wv*24 + 2*q  )*64 + lane] = pkrtz(v.x, v.y);
      xall[(wv*24 + 2*q+1)*64 + lane] = pkrtz(v.z, v.w);
    }
  }
  for(int i=tid;i<24*64;i+=384) hb[0][i]=0u;

  float rb[8], zb[8], nbi[8], nbh[8], hprev[8];
#pragma unroll
  for(int j=0;j<8;j++){
    rb[j] = bih[f0+j]    + bhh[f0+j];
    zb[j] = bih[48+f0+j] + bhh[48+f0+j];
    nbi[j]= bih[96+f0+j];
    nbh[j]= bhh[96+f0+j];
    hprev[j]=0.f;
  }
  __syncthreads();   // xall + hb[0] ready

  int cur=0;
  for(int t=0;t<TT;t++){
    // acc[0..7]=r (both biases), [8..15]=z (both), [16..23]=h-side n; accn = x-side n
    float acc[24], accn[8];
#pragma unroll
    for(int j=0;j<8;j++){ acc[j]=rb[j]; acc[8+j]=zb[j]; acc[16+j]=nbh[j]; accn[j]=nbi[j]; }
    const unsigned* hbc = &hb[cur][0];
    const unsigned* xtc = &xall[t*24*64];
#pragma unroll 2
    for(int k2=0;k2<24;k2++){
      const unsigned* wp = Wall + (wv*24+k2)*48;
      unsigned ws[48];
#pragma unroll
      for(int q=0;q<48;q++) ws[q]=wp[q];       // uniform -> s_load
      unsigned h2k = hbc[k2*64+lane];
      unsigned xk  = xtc[k2*64+lane];
#pragma unroll
      for(int c=0;c<24;c++) acc[c]  = dot2f(h2k, ws[c],    acc[c]);
#pragma unroll
      for(int c=0;c<16;c++) acc[c]  = dot2f(xk,  ws[24+c], acc[c]);
#pragma unroll
      for(int c=0;c<8;c++)  accn[c] = dot2f(xk,  ws[40+c], accn[c]);
    }
    unsigned* hw = &hb[cur^1][0];
    float hn[8];
#pragma unroll
    for(int j=0;j<8;j++){
      float r  = sigmoidf_(acc[j]);
      float zg = sigmoidf_(acc[8+j]);
      float ng = tanhf_(accn[j] + r*acc[16+j]);
      float hv = (1.f-zg)*ng + zg*hprev[j];
      hprev[j]=hv; hn[j]=hv;
    }
#pragma unroll
    for(int m=0;m<4;m++) hw[(wv*4+m)*64+lane] = pack2h(hn[2*m], hn[2*m+1]);
    __syncthreads();   // next buffer fully written
    cur^=1;
  }

  // classifier epilogue: wave 0 covers the block's 64 nodes
  if(wv==0 && n<NN){
    const unsigned* hbc=&hb[cur][0];
    float hv[24];
#pragma unroll
    for(int j=0;j<24;j++) hv[j]=bc1[j];
#pragma unroll 2
    for(int k2=0;k2<24;k2++){
      unsigned u = hbc[k2*64+lane];
      float hk0 = h2f(u), hk1 = h2f(u>>16);
      const float* w0 = Wc1 + (2*k2)*24;     // uniform -> s_load
      const float* w1 = Wc1 + (2*k2+1)*24;
#pragma unroll
      for(int j=0;j<24;j++) hv[j] = fmaf(hk0, w0[j], hv[j]);
#pragma unroll
      for(int j=0;j<24;j++) hv[j] = fmaf(hk1, w1[j], hv[j]);
    }
    float l0=bc2[0], l1=bc2[1];
#pragma unroll
    for(int j=0;j<24;j++){
      float a = fmaxf(hv[j],0.f);
      l0 = fmaf(a, Wc2[2*j],   l0);
      l1 = fmaf(a, Wc2[2*j+1], l1);
    }
    reinterpret_cast<float2*>(out)[n] = make_float2(l0,l1);
  }
}

static inline size_t al256(size_t x){ return (x+255)&~(size_t)255; }

extern "C" void kernel_launch(void* const* d_in, const int* in_sizes, int n_in,
                              void* d_out, int out_size, void* d_ws, size_t ws_size,
                              hipStream_t stream){
  const float* x_seq=(const float*)d_in[0];
  const int*   ei   =(const int*)d_in[1];
  const float* ew   =(const float*)d_in[2];
  const float* W0=(const float*)d_in[3];  const float* b0=(const float*)d_in[4];
  const float* g0=(const float*)d_in[5];  const float* be0=(const float*)d_in[6];
  const float* W1=(const float*)d_in[7];  const float* b1=(const float*)d_in[8];
  const float* g1=(const float*)d_in[9];  const float* be1=(const float*)d_in[10];
  const float* Wih=(const float*)d_in[11];const float* Whh=(const float*)d_in[12];
  const float* bih=(const float*)d_in[13];const float* bhh=(const float*)d_in[14];
  const float* Wc1=(const float*)d_in[15];const float* bc1=(const float*)d_in[16];
  const float* Wc2=(const float*)d_in[17];const float* bc2=(const float*)d_in[18];
  float* outp=(float*)d_out;

  char* p=(char*)d_ws; size_t off=0;
  auto alloc=[&](size_t bytes)->void*{ void* r=p+off; off=al256(off+bytes); return r; };
  float* dis    =(float*)alloc((size_t)NN*4);   // degf during build, then rsqrt'd in k_partA
  int*   cnt    =(int*)  alloc((size_t)NN*4);
  int*   offs   =(int*)  alloc((size_t)(NN+1)*4);
  int*   bsum   =(int*)  alloc((size_t)NB*4);
  int*   bpre   =(int*)  alloc((size_t)NB*4);
  int*   pos    =(int*)  alloc((size_t)NE*4);
  int2*  csr    =(int2*) alloc((size_t)NE*8);
  unsigned* Wall=(unsigned*)alloc((size_t)6*24*48*4);
  unsigned* A   =(unsigned*)alloc((size_t)NN*576 + 1024);   // bf16 [n][f][t6], 576B/row
  float* h1     =(float*)alloc((size_t)NN*TT*HID*4);
  float* h2     =(float*)alloc((size_t)NN*TT*HID*4);

  const int GN=(NN+255)/256, GE=(NE+255)/256;
  const int GMM=(NN+63)/64;              // 64 nodes/block
  const int GAGG=(NN*64+255)/256;        // 1 wave/node
  const int GGRU=(NN+63)/64;             // 64 nodes/block, 6 waves

  k_setup  <<<GN,256,0,stream>>>(cnt,dis,Wih,Whh,Wall);
  k_cnt    <<<GE,256,0,stream>>>(ei,ew,cnt,dis,pos);
  k_partA  <<<NB,256,0,stream>>>(cnt,bsum,dis);
  k_midB   <<<1,256,0,stream>>>(bsum,bpre,offs);
  k_offsC  <<<NB,256,0,stream>>>(cnt,bpre,offs);
  k_scatter<<<GE,256,0,stream>>>(ei,ew,offs,pos,dis,csr);

  // layer 0
  k_mm0<<<GMM,256,0,stream>>>(x_seq, W0, A);
  k_agg<<<GAGG,256,0,stream>>>(A,b0,g0,be0,nullptr,h1,offs,csr,dis);
  // layer 1 (residual = h1)
  k_mm1<<<GMM,256,0,stream>>>(h1, W1, A);
  k_agg<<<GAGG,256,0,stream>>>(A,b1,g1,be1,h1,h2,offs,csr,dis);
  // fused GRU (x-side + h-side) + classifier
  k_gruF2<<<GGRU,384,0,stream>>>(h2, Wall, bih,bhh, Wc1,bc1,Wc2,bc2, outp);
}

// Round 8
// 635.079 us; speedup vs baseline: 1.1448x; 1.1448x over previous
//
#include <hip/hip_runtime.h>
#include <hip/hip_fp16.h>
#include <math.h>

#define NN 50000
#define NE 800000
#define TT 6
#define HID 48
#define NB 196   // (NN+255)/256

__device__ __forceinline__ float sigmoidf_(float x){ return 1.0f/(1.0f+__expf(-x)); }
__device__ __forceinline__ float tanhf_(float x){
  float xc = fminf(fmaxf(x,-15.f),15.f);
  float t = __expf(2.f*xc);
  return (t-1.f)/(t+1.f);
}
__device__ __forceinline__ unsigned f2bf(float x){
  unsigned u = __float_as_uint(x);
  return (u + 0x7fffu + ((u>>16)&1u)) >> 16;   // RNE to bf16
}
__device__ __forceinline__ unsigned pack2(float a, float b){
  return f2bf(a) | (f2bf(b)<<16);
}
__device__ __forceinline__ float bflo(unsigned u){ return __uint_as_float(u<<16); }
__device__ __forceinline__ float bfhi(unsigned u){ return __uint_as_float(u & 0xffff0000u); }
__device__ __forceinline__ unsigned f2h(float x){
  return (unsigned)__half_as_ushort(__float2half(x));   // RNE fp16
}
__device__ __forceinline__ float h2f(unsigned u){
  return __half2float(__ushort_as_half((unsigned short)(u & 0xffffu)));
}
__device__ __forceinline__ unsigned pack2h(float a, float b){   // RNE fp16 pair
  return f2h(a) | (f2h(b)<<16);
}

typedef __fp16 h2t __attribute__((ext_vector_type(2)));

__device__ __forceinline__ unsigned pkrtz(float a, float b){    // fast packed cvt (RTZ)
#if __has_builtin(__builtin_amdgcn_cvt_pkrtz)
  auto r = __builtin_amdgcn_cvt_pkrtz(a, b);
  return __builtin_bit_cast(unsigned, r);
#else
  return pack2h(a, b);
#endif
}
// acc += lo(a)*lo(b) + hi(a)*hi(b), fp32 accumulate
__device__ __forceinline__ float dot2f(unsigned a, unsigned b, float c){
#if __has_builtin(__builtin_amdgcn_fdot2)
  return __builtin_amdgcn_fdot2(__builtin_bit_cast(h2t, a), __builtin_bit_cast(h2t, b), c, false);
#else
  h2t av = __builtin_bit_cast(h2t, a), bv = __builtin_bit_cast(h2t, b);
  return c + (float)av[0]*(float)bv[0] + (float)av[1]*(float)bv[1];
#endif
}

struct U3 { unsigned x,y,z; };

// 256-thread inclusive block scan (4 waves of 64)
__device__ __forceinline__ int block_scan_incl(int x, int* wsum){
  int lane = threadIdx.x & 63, w = threadIdx.x >> 6;
  int v = x;
#pragma unroll
  for(int d=1; d<64; d<<=1){
    int u = __shfl_up(v, d, 64);
    if(lane >= d) v += u;
  }
  if(lane==63) wsum[w] = v;
  __syncthreads();
  int add = 0;
#pragma unroll
  for(int k=0;k<3;k++) if(w>k) add += wsum[k];
  return v + add;
}

// ---------------- setup: cnt init + GRU weight repack (fp16 pairs along k) ----------------
// Wall [6 wv][24 k2][48 c] u32:
//   c<24  : h-side, row map: c<8 -> r (wv*8+c), c<16 -> z (48+wv*8+c-8), else n (96+wv*8+c-16)
//   c>=24 : x-side, same row map on (c-24), from Wih.
__global__ __launch_bounds__(256) void k_setup(int* cnt,
                                               const float* __restrict__ Wih, const float* __restrict__ Whh,
                                               unsigned* Wall){
  int i = blockIdx.x*256+threadIdx.x;
  if(i<NN) cnt[i]=0;
  if(i < 6*24*48){
    int wv = i/1152, r = i%1152;
    int k2 = r/48, c = r%48;
    int cc = (c<24)? c : (c-24);
    int row = (cc<8) ? (wv*8 + cc) : (cc<16) ? (48 + wv*8 + cc-8) : (96 + wv*8 + cc-16);
    const float* Wsrc = (c<24)? Whh : Wih;
    Wall[i] = pack2h(Wsrc[row*48 + 2*k2], Wsrc[row*48 + 2*k2 + 1]);
  }
}

// single atomic per edge: rank within destination bucket
__global__ __launch_bounds__(256) void k_cnt(const int* __restrict__ ei, int* cnt, int* pos){
  int e = blockIdx.x*256+threadIdx.x;
  if(e<NE){
    int c = ei[NE+e];
    pos[e] = atomicAdd(&cnt[c], 1);
  }
}

// phase A: per-block sums of cnt
__global__ __launch_bounds__(256) void k_partA(const int* __restrict__ cnt, int* bsum){
  __shared__ int wsum[4];
  int i = blockIdx.x*256+threadIdx.x;
  int x = (i<NN)? cnt[i] : 0;
  int lane = threadIdx.x & 63, w = threadIdx.x >> 6;
  int v = x;
#pragma unroll
  for(int m=32;m>=1;m>>=1) v += __shfl_xor(v, m, 64);
  if(lane==0) wsum[w]=v;
  __syncthreads();
  if(threadIdx.x==0) bsum[blockIdx.x] = wsum[0]+wsum[1]+wsum[2]+wsum[3];
}

// phase B: exclusive scan of 196 block sums
__global__ __launch_bounds__(256) void k_midB(const int* __restrict__ bsum, int* bpre, int* offs){
  __shared__ int wsum[4];
  int t = threadIdx.x;
  int x = (t<NB)? bsum[t] : 0;
  int incl = block_scan_incl(x, wsum);
  if(t<NB) bpre[t] = incl - x;
  if(t==255) offs[NN] = incl;   // total
}

// phase C: per-block exclusive scan of cnt + bpre -> offs
__global__ __launch_bounds__(256) void k_offsC(const int* __restrict__ cnt, const int* __restrict__ bpre,
                                               int* offs){
  __shared__ int wsum[4];
  int i = blockIdx.x*256+threadIdx.x;
  int x = (i<NN)? cnt[i] : 0;
  int incl = block_scan_incl(x, wsum);
  if(i<NN) offs[i] = bpre[blockIdx.x] + incl - x;
}

// atomic-free scatter: csr[offs[c]+pos[e]] = (row, ew)
__global__ __launch_bounds__(256) void k_scatter(const int* __restrict__ ei, const float* __restrict__ ew,
                                                 const int* __restrict__ offs, const int* __restrict__ pos,
                                                 int2* __restrict__ csr){
  int e = blockIdx.x*256+threadIdx.x;
  if(e<NE){
    int c = ei[NE+e];
    int2 v; v.x = ei[e]; v.y = __float_as_int(ew[e]);
    csr[offs[c]+pos[e]] = v;
  }
}

// deg = 1 + row-sum of ew (atomic-free), dis = rsqrt(deg)  [deg>=1 always]
__global__ __launch_bounds__(256) void k_deg(const int2* __restrict__ csr, const int* __restrict__ offs,
                                             float* dis){
  int i = blockIdx.x*256+threadIdx.x;
  if(i<NN){
    float s = 1.f;
    int e0=offs[i], e1=offs[i+1];
    for(int j=e0;j<e1;j++) s += __int_as_float(csr[j].y);
    dis[i] = rsqrtf(s);
  }
}

// patch edge norm in place: y = dis[r]*ew   (dis[c] factored out in k_agg)
__global__ __launch_bounds__(256) void k_normE(int2* __restrict__ csr, const float* __restrict__ dis){
  int j = blockIdx.x*256+threadIdx.x;
  if(j<NE){
    int2 v = csr[j];
    v.y = __float_as_int(dis[v.x]*__int_as_float(v.y));
    csr[j] = v;
  }
}

// ---------------- layer-0 matmul: wave = feature slice (uniform), lane = node ----------------
// t-OUTER loop: each lane consumes its 64B cache lines in 4 consecutive k4 iterations
// (per-wave L1 window 4 KB vs 24 KB for t-inner) — kills the L1 thrash on the 77 MB input.
// A row per node = 144 words (576B): feature f at word offset f*3, bf16 [t6].
__global__ __launch_bounds__(256) void k_mm0(const float* __restrict__ X, const float* __restrict__ W,
                                             unsigned* __restrict__ A){
  int s = __builtin_amdgcn_readfirstlane(threadIdx.x>>6);   // 0..3, wave-uniform
  int n = blockIdx.x*64 + (threadIdx.x&63);
  if(n>=NN) return;
  const float* xb = X + (long long)n*64;
  const float* wb = W + 12*s;
  float acc[TT][12];
#pragma unroll
  for(int t=0;t<TT;t++)
#pragma unroll
    for(int j=0;j<12;j++) acc[t][j]=0.f;
#pragma unroll
  for(int t=0;t<TT;t++){                 // full unroll: acc[t] constant-indexed
    const float* xt = xb + (long long)t*NN*64;
#pragma unroll 2
    for(int k4=0;k4<16;k4++){
      float4 xv = *reinterpret_cast<const float4*>(xt + 4*k4);
#pragma unroll
      for(int q=0;q<4;q++){
        const float* wr = wb + (4*k4+q)*HID;
        float w[12];
#pragma unroll
        for(int j=0;j<12;j++) w[j]=wr[j];   // uniform addr -> s_load (sK$-resident, re-streamed per t)
        float xs = (&xv.x)[q];
#pragma unroll
        for(int j=0;j<12;j++) acc[t][j] = fmaf(xs, w[j], acc[t][j]);
      }
    }
  }
  unsigned buf[36];
#pragma unroll
  for(int j=0;j<12;j++){
    buf[3*j  ]=pack2(acc[0][j],acc[1][j]);
    buf[3*j+1]=pack2(acc[2][j],acc[3][j]);
    buf[3*j+2]=pack2(acc[4][j],acc[5][j]);
  }
  uint4* o4 = reinterpret_cast<uint4*>(A + (long long)n*144 + 36*s);
#pragma unroll
  for(int q=0;q<9;q++) o4[q] = make_uint4(buf[4*q],buf[4*q+1],buf[4*q+2],buf[4*q+3]);
}

// ---------------- layer-1 matmul (K=48), input fp32 [n][t][48], t-outer ----------------
__global__ __launch_bounds__(256) void k_mm1(const float* __restrict__ X, const float* __restrict__ W,
                                             unsigned* __restrict__ A){
  int s = __builtin_amdgcn_readfirstlane(threadIdx.x>>6);
  int n = blockIdx.x*64 + (threadIdx.x&63);
  if(n>=NN) return;
  const float* xb = X + (long long)n*(TT*HID);
  const float* wb = W + 12*s;
  float acc[TT][12];
#pragma unroll
  for(int t=0;t<TT;t++)
#pragma unroll
    for(int j=0;j<12;j++) acc[t][j]=0.f;
#pragma unroll
  for(int t=0;t<TT;t++){                 // full unroll: acc[t] constant-indexed
    const float* xt = xb + t*HID;
#pragma unroll 2
    for(int k4=0;k4<12;k4++){
      float4 xv = *reinterpret_cast<const float4*>(xt + 4*k4);
#pragma unroll
      for(int q=0;q<4;q++){
        const float* wr = wb + (4*k4+q)*HID;
        float w[12];
#pragma unroll
        for(int j=0;j<12;j++) w[j]=wr[j];
        float xs = (&xv.x)[q];
#pragma unroll
        for(int j=0;j<12;j++) acc[t][j] = fmaf(xs, w[j], acc[t][j]);
      }
    }
  }
  unsigned buf[36];
#pragma unroll
  for(int j=0;j<12;j++){
    buf[3*j  ]=pack2(acc[0][j],acc[1][j]);
    buf[3*j+1]=pack2(acc[2][j],acc[3][j]);
    buf[3*j+2]=pack2(acc[4][j],acc[5][j]);
  }
  uint4* o4 = reinterpret_cast<uint4*>(A + (long long)n*144 + 36*s);
#pragma unroll
  for(int q=0;q<9;q++) o4[q] = make_uint4(buf[4*q],buf[4*q+1],buf[4*q+2],buf[4*q+3]);
}

// ---------------- CSR aggregation (bf16 gather) + bias + LN + ReLU (+resid)
// edge norm stored = dis[r]*ew ; dis[c] factored: out = dn*(Σ nr*x_r + dn*x_c)
__global__ __launch_bounds__(256) void k_agg(const unsigned* __restrict__ A, const float* __restrict__ bias,
                                             const float* __restrict__ gain, const float* __restrict__ beta,
                                             const float* __restrict__ resid, float* __restrict__ out,
                                             const int* __restrict__ offs, const int2* __restrict__ csr,
                                             const float* __restrict__ dis){
  int wid = (blockIdx.x*256+threadIdx.x)>>6;
  int lane = threadIdx.x & 63;
  if(wid>=NN) return;
  const bool act = lane<HID;
  const int f = act? lane : (HID-1);
  float dn = dis[wid];
  float acc[TT];
  {
    U3 v = *reinterpret_cast<const U3*>(A + (long long)wid*144 + 3*f);
    acc[0]=dn*bflo(v.x); acc[1]=dn*bfhi(v.x);
    acc[2]=dn*bflo(v.y); acc[3]=dn*bfhi(v.y);
    acc[4]=dn*bflo(v.z); acc[5]=dn*bfhi(v.z);
  }
  int e0=offs[wid], e1=offs[wid+1];
  int e=e0;
  for(; e+3<e1; e+=4){
    int2 i0=csr[e], i1=csr[e+1], i2=csr[e+2], i3=csr[e+3];
    U3 d0 = *reinterpret_cast<const U3*>(A + (long long)i0.x*144 + 3*f);
    U3 d1 = *reinterpret_cast<const U3*>(A + (long long)i1.x*144 + 3*f);
    U3 d2 = *reinterpret_cast<const U3*>(A + (long long)i2.x*144 + 3*f);
    U3 d3 = *reinterpret_cast<const U3*>(A + (long long)i3.x*144 + 3*f);
    float n0=__int_as_float(i0.y), n1=__int_as_float(i1.y);
    float n2=__int_as_float(i2.y), n3=__int_as_float(i3.y);
    acc[0]=fmaf(n0,bflo(d0.x),acc[0]); acc[1]=fmaf(n0,bfhi(d0.x),acc[1]);
    acc[2]=fmaf(n0,bflo(d0.y),acc[2]); acc[3]=fmaf(n0,bfhi(d0.y),acc[3]);
    acc[4]=fmaf(n0,bflo(d0.z),acc[4]); acc[5]=fmaf(n0,bfhi(d0.z),acc[5]);
    acc[0]=fmaf(n1,bflo(d1.x),acc[0]); acc[1]=fmaf(n1,bfhi(d1.x),acc[1]);
    acc[2]=fmaf(n1,bflo(d1.y),acc[2]); acc[3]=fmaf(n1,bfhi(d1.y),acc[3]);
    acc[4]=fmaf(n1,bflo(d1.z),acc[4]); acc[5]=fmaf(n1,bfhi(d1.z),acc[5]);
    acc[0]=fmaf(n2,bflo(d2.x),acc[0]); acc[1]=fmaf(n2,bfhi(d2.x),acc[1]);
    acc[2]=fmaf(n2,bflo(d2.y),acc[2]); acc[3]=fmaf(n2,bfhi(d2.y),acc[3]);
    acc[4]=fmaf(n2,bflo(d2.z),acc[4]); acc[5]=fmaf(n2,bfhi(d2.z),acc[5]);
    acc[0]=fmaf(n3,bflo(d3.x),acc[0]); acc[1]=fmaf(n3,bfhi(d3.x),acc[1]);
    acc[2]=fmaf(n3,bflo(d3.y),acc[2]); acc[3]=fmaf(n3,bfhi(d3.y),acc[3]);
    acc[4]=fmaf(n3,bflo(d3.z),acc[4]); acc[5]=fmaf(n3,bfhi(d3.z),acc[5]);
  }
  for(; e<e1; ++e){
    int2 i0=csr[e];
    U3 d0 = *reinterpret_cast<const U3*>(A + (long long)i0.x*144 + 3*f);
    float n0=__int_as_float(i0.y);
    acc[0]=fmaf(n0,bflo(d0.x),acc[0]); acc[1]=fmaf(n0,bfhi(d0.x),acc[1]);
    acc[2]=fmaf(n0,bflo(d0.y),acc[2]); acc[3]=fmaf(n0,bfhi(d0.y),acc[3]);
    acc[4]=fmaf(n0,bflo(d0.z),acc[4]); acc[5]=fmaf(n0,bfhi(d0.z),acc[5]);
  }
  float bb = bias[f], gg = gain[f], be = beta[f];
  const float rn = 1.0f/HID;
#pragma unroll
  for(int t=0;t<TT;t++){
    float val = fmaf(acc[t], dn, bb);    // final *dn fold
    float v = act? val : 0.f;
    float s = v, s2 = v*v;
#pragma unroll
    for(int m=32;m>=1;m>>=1){
      s  += __shfl_xor(s,  m, 64);
      s2 += __shfl_xor(s2, m, 64);
    }
    float mu  = s*rn;
    float var = fmaxf(s2*rn - mu*mu, 0.f);
    float y = (val-mu)*rsqrtf(var+1e-5f)*gg + be;
    y = fmaxf(y, 0.f);
    long long oidx = (long long)wid*(TT*HID) + t*HID + f;
    if(resid) y += resid[oidx];
    if(act) out[oidx] = y;
  }
}

// ---------------- fused GRU (x-side + h-side, fp16 dot2) + classifier [r5 proven shape] ----------
// block: 64 nodes, 384 threads = 6 waves. Wave wv owns 8 features, lane = node.
// x (all 6 steps) staged ONCE into LDS as fp16 pairs [t][k2][lane] (36 KB);
// h double-buffered fp16 [2][24][64] (12 KB). k-loop: ds_read_b32 x2 + ws[48] s_load
// + 48 dot2, unroll 2.
__global__ __launch_bounds__(384) void k_gruF2(const float* __restrict__ X,     // h2 [n][t][48]
                                               const unsigned* __restrict__ Wall, // [6][24][48] u32
                                               const float* __restrict__ bih, const float* __restrict__ bhh,
                                               const float* __restrict__ Wc1, const float* __restrict__ bc1,
                                               const float* __restrict__ Wc2, const float* __restrict__ bc2,
                                               float* __restrict__ out){
  __shared__ unsigned xall[TT*24*64];   // 36 KB
  __shared__ unsigned hb[2][24*64];     // 12 KB
  int tid = threadIdx.x;
  int wv = __builtin_amdgcn_readfirstlane(tid>>6);   // 0..5, uniform
  int lane = tid & 63;
  int f0 = wv*8;
  long long n = (long long)blockIdx.x*64 + lane;
  long long gn = (n<NN)? n : (NN-1);

  // stage x: wave wv stages timestep wv (12 float4 loads -> 24 packed writes)
  {
    const float* xb = X + gn*(TT*HID) + wv*HID;
#pragma unroll
    for(int q=0;q<12;q++){
      float4 v = *reinterpret_cast<const float4*>(xb + 4*q);
      xall[(wv*24 + 2*q  )*64 + lane] = pkrtz(v.x, v.y);
      xall[(wv*24 + 2*q+1)*64 + lane] = pkrtz(v.z, v.w);
    }
  }
  for(int i=tid;i<24*64;i+=384) hb[0][i]=0u;

  float rb[8], zb[8], nbi[8], nbh[8], hprev[8];
#pragma unroll
  for(int j=0;j<8;j++){
    rb[j] = bih[f0+j]    + bhh[f0+j];
    zb[j] = bih[48+f0+j] + bhh[48+f0+j];
    nbi[j]= bih[96+f0+j];
    nbh[j]= bhh[96+f0+j];
    hprev[j]=0.f;
  }
  __syncthreads();   // xall + hb[0] ready

  int cur=0;
  for(int t=0;t<TT;t++){
    // acc[0..7]=r (both biases), [8..15]=z (both), [16..23]=h-side n; accn = x-side n
    float acc[24], accn[8];
#pragma unroll
    for(int j=0;j<8;j++){ acc[j]=rb[j]; acc[8+j]=zb[j]; acc[16+j]=nbh[j]; accn[j]=nbi[j]; }
    const unsigned* hbc = &hb[cur][0];
    const unsigned* xtc = &xall[t*24*64];
#pragma unroll 2
    for(int k2=0;k2<24;k2++){
      const unsigned* wp = Wall + (wv*24+k2)*48;
      unsigned ws[48];
#pragma unroll
      for(int q=0;q<48;q++) ws[q]=wp[q];       // uniform -> s_load
      unsigned h2k = hbc[k2*64+lane];
      unsigned xk  = xtc[k2*64+lane];
#pragma unroll
      for(int c=0;c<24;c++) acc[c]  = dot2f(h2k, ws[c],    acc[c]);
#pragma unroll
      for(int c=0;c<16;c++) acc[c]  = dot2f(xk,  ws[24+c], acc[c]);
#pragma unroll
      for(int c=0;c<8;c++)  accn[c] = dot2f(xk,  ws[40+c], accn[c]);
    }
    unsigned* hw = &hb[cur^1][0];
    float hn[8];
#pragma unroll
    for(int j=0;j<8;j++){
      float r  = sigmoidf_(acc[j]);
      float zg = sigmoidf_(acc[8+j]);
      float ng = tanhf_(accn[j] + r*acc[16+j]);
      float hv = (1.f-zg)*ng + zg*hprev[j];
      hprev[j]=hv; hn[j]=hv;
    }
#pragma unroll
    for(int m=0;m<4;m++) hw[(wv*4+m)*64+lane] = pack2h(hn[2*m], hn[2*m+1]);
    __syncthreads();   // next buffer fully written
    cur^=1;
  }

  // classifier epilogue: wave 0 covers the block's 64 nodes
  if(wv==0 && n<NN){
    const unsigned* hbc=&hb[cur][0];
    float hv[24];
#pragma unroll
    for(int j=0;j<24;j++) hv[j]=bc1[j];
#pragma unroll 2
    for(int k2=0;k2<24;k2++){
      unsigned u = hbc[k2*64+lane];
      float hk0 = h2f(u), hk1 = h2f(u>>16);
      const float* w0 = Wc1 + (2*k2)*24;     // uniform -> s_load
      const float* w1 = Wc1 + (2*k2+1)*24;
#pragma unroll
      for(int j=0;j<24;j++) hv[j] = fmaf(hk0, w0[j], hv[j]);
#pragma unroll
      for(int j=0;j<24;j++) hv[j] = fmaf(hk1, w1[j], hv[j]);
    }
    float l0=bc2[0], l1=bc2[1];
#pragma unroll
    for(int j=0;j<24;j++){
      float a = fmaxf(hv[j],0.f);
      l0 = fmaf(a, Wc2[2*j],   l0);
      l1 = fmaf(a, Wc2[2*j+1], l1);
    }
    reinterpret_cast<float2*>(out)[n] = make_float2(l0,l1);
  }
}

static inline size_t al256(size_t x){ return (x+255)&~(size_t)255; }

extern "C" void kernel_launch(void* const* d_in, const int* in_sizes, int n_in,
                              void* d_out, int out_size, void* d_ws, size_t ws_size,
                              hipStream_t stream){
  const float* x_seq=(const float*)d_in[0];
  const int*   ei   =(const int*)d_in[1];
  const float* ew   =(const float*)d_in[2];
  const float* W0=(const float*)d_in[3];  const float* b0=(const float*)d_in[4];
  const float* g0=(const float*)d_in[5];  const float* be0=(const float*)d_in[6];
  const float* W1=(const float*)d_in[7];  const float* b1=(const float*)d_in[8];
  const float* g1=(const float*)d_in[9];  const float* be1=(const float*)d_in[10];
  const float* Wih=(const float*)d_in[11];const float* Whh=(const float*)d_in[12];
  const float* bih=(const float*)d_in[13];const float* bhh=(const float*)d_in[14];
  const float* Wc1=(const float*)d_in[15];const float* bc1=(const float*)d_in[16];
  const float* Wc2=(const float*)d_in[17];const float* bc2=(const float*)d_in[18];
  float* outp=(float*)d_out;

  char* p=(char*)d_ws; size_t off=0;
  auto alloc=[&](size_t bytes)->void*{ void* r=p+off; off=al256(off+bytes); return r; };
  float* dis    =(float*)alloc((size_t)NN*4);
  int*   cnt    =(int*)  alloc((size_t)NN*4);
  int*   offs   =(int*)  alloc((size_t)(NN+1)*4);
  int*   bsum   =(int*)  alloc((size_t)NB*4);
  int*   bpre   =(int*)  alloc((size_t)NB*4);
  int*   pos    =(int*)  alloc((size_t)NE*4);
  int2*  csr    =(int2*) alloc((size_t)NE*8);
  unsigned* Wall=(unsigned*)alloc((size_t)6*24*48*4);
  unsigned* A   =(unsigned*)alloc((size_t)NN*576 + 1024);   // bf16 [n][f][t6], 576B/row
  float* h1     =(float*)alloc((size_t)NN*TT*HID*4);
  float* h2     =(float*)alloc((size_t)NN*TT*HID*4);

  const int GN=(NN+255)/256, GE=(NE+255)/256;
  const int GMM=(NN+63)/64;              // 64 nodes/block
  const int GAGG=(NN*64+255)/256;        // 1 wave/node
  const int GGRU=(NN+63)/64;             // 64 nodes/block, 6 waves

  k_setup  <<<GN,256,0,stream>>>(cnt,Wih,Whh,Wall);
  k_cnt    <<<GE,256,0,stream>>>(ei,cnt,pos);
  k_partA  <<<NB,256,0,stream>>>(cnt,bsum);
  k_midB   <<<1,256,0,stream>>>(bsum,bpre,offs);
  k_offsC  <<<NB,256,0,stream>>>(cnt,bpre,offs);
  k_scatter<<<GE,256,0,stream>>>(ei,ew,offs,pos,csr);
  k_deg    <<<GN,256,0,stream>>>(csr,offs,dis);
  k_normE  <<<GE,256,0,stream>>>(csr,dis);

  // layer 0
  k_mm0<<<GMM,256,0,stream>>>(x_seq, W0, A);
  k_agg<<<GAGG,256,0,stream>>>(A,b0,g0,be0,nullptr,h1,offs,csr,dis);
  // layer 1 (residual = h1)
  k_mm1<<<GMM,256,0,stream>>>(h1, W1, A);
  k_agg<<<GAGG,256,0,stream>>>(A,b1,g1,be1,h1,h2,offs,csr,dis);
  // fused GRU (x-side + h-side) + classifier
  k_gruF2<<<GGRU,384,0,stream>>>(h2, Wall, bih,bhh, Wc1,bc1,Wc2,bc2, outp);
}

// Round 9
// 614.056 us; speedup vs baseline: 1.1840x; 1.0342x over previous
//
#include <hip/hip_runtime.h>
#include <hip/hip_fp16.h>
#include <math.h>

#define NN 50000
#define NE 800000
#define TT 6
#define HID 48
#define NB 196   // (NN+255)/256

__device__ __forceinline__ float sigmoidf_(float x){ return 1.0f/(1.0f+__expf(-x)); }
__device__ __forceinline__ float tanhf_(float x){
  float xc = fminf(fmaxf(x,-15.f),15.f);
  float t = __expf(2.f*xc);
  return (t-1.f)/(t+1.f);
}
__device__ __forceinline__ unsigned f2bf(float x){
  unsigned u = __float_as_uint(x);
  return (u + 0x7fffu + ((u>>16)&1u)) >> 16;   // RNE to bf16
}
__device__ __forceinline__ unsigned pack2(float a, float b){
  return f2bf(a) | (f2bf(b)<<16);
}
__device__ __forceinline__ float bflo(unsigned u){ return __uint_as_float(u<<16); }
__device__ __forceinline__ float bfhi(unsigned u){ return __uint_as_float(u & 0xffff0000u); }
__device__ __forceinline__ unsigned f2h(float x){
  return (unsigned)__half_as_ushort(__float2half(x));   // RNE fp16
}
__device__ __forceinline__ float h2f(unsigned u){
  return __half2float(__ushort_as_half((unsigned short)(u & 0xffffu)));
}
__device__ __forceinline__ unsigned pack2h(float a, float b){   // RNE fp16 pair
  return f2h(a) | (f2h(b)<<16);
}

typedef __fp16 h2t __attribute__((ext_vector_type(2)));

__device__ __forceinline__ unsigned pkrtz(float a, float b){    // fast packed cvt (RTZ)
#if __has_builtin(__builtin_amdgcn_cvt_pkrtz)
  auto r = __builtin_amdgcn_cvt_pkrtz(a, b);
  return __builtin_bit_cast(unsigned, r);
#else
  return pack2h(a, b);
#endif
}
// acc += lo(a)*lo(b) + hi(a)*hi(b), fp32 accumulate
__device__ __forceinline__ float dot2f(unsigned a, unsigned b, float c){
#if __has_builtin(__builtin_amdgcn_fdot2)
  return __builtin_amdgcn_fdot2(__builtin_bit_cast(h2t, a), __builtin_bit_cast(h2t, b), c, false);
#else
  h2t av = __builtin_bit_cast(h2t, a), bv = __builtin_bit_cast(h2t, b);
  return c + (float)av[0]*(float)bv[0] + (float)av[1]*(float)bv[1];
#endif
}

struct U3 { unsigned x,y,z; };

// 256-thread inclusive block scan (4 waves of 64)
__device__ __forceinline__ int block_scan_incl(int x, int* wsum){
  int lane = threadIdx.x & 63, w = threadIdx.x >> 6;
  int v = x;
#pragma unroll
  for(int d=1; d<64; d<<=1){
    int u = __shfl_up(v, d, 64);
    if(lane >= d) v += u;
  }
  if(lane==63) wsum[w] = v;
  __syncthreads();
  int add = 0;
#pragma unroll
  for(int k=0;k<3;k++) if(w>k) add += wsum[k];
  return v + add;
}

// ---------------- setup: cnt init + GRU weight repack (fp16 pairs along k) ----------------
// W2 [12 w][24 k2][24 c] u32: wave w owns hidden features 4w..4w+3.
//   c<12 : h-side (Whh), cc=c:   cc<4 -> r-row (4w+cc), cc<8 -> z-row (48+4w+cc-4), else n-row (96+4w+cc-8)
//   c>=12: x-side (Wih), cc=c-12, same row map.
__global__ __launch_bounds__(256) void k_setup(int* cnt,
                                               const float* __restrict__ Wih, const float* __restrict__ Whh,
                                               unsigned* W2){
  int i = blockIdx.x*256+threadIdx.x;
  if(i<NN) cnt[i]=0;
  if(i < 12*24*24){
    int w = i/576, r = i%576;
    int k2 = r/24, c = r%24;
    int cc = (c<12)? c : (c-12);
    int row = (cc<4) ? (w*4 + cc) : (cc<8) ? (48 + w*4 + cc-4) : (96 + w*4 + cc-8);
    const float* Wsrc = (c<12)? Whh : Wih;
    W2[i] = pack2h(Wsrc[row*48 + 2*k2], Wsrc[row*48 + 2*k2 + 1]);
  }
}

// single atomic per edge: rank within destination bucket
__global__ __launch_bounds__(256) void k_cnt(const int* __restrict__ ei, int* cnt, int* pos){
  int e = blockIdx.x*256+threadIdx.x;
  if(e<NE){
    int c = ei[NE+e];
    pos[e] = atomicAdd(&cnt[c], 1);
  }
}

// phase A: per-block sums of cnt
__global__ __launch_bounds__(256) void k_partA(const int* __restrict__ cnt, int* bsum){
  __shared__ int wsum[4];
  int i = blockIdx.x*256+threadIdx.x;
  int x = (i<NN)? cnt[i] : 0;
  int lane = threadIdx.x & 63, w = threadIdx.x >> 6;
  int v = x;
#pragma unroll
  for(int m=32;m>=1;m>>=1) v += __shfl_xor(v, m, 64);
  if(lane==0) wsum[w]=v;
  __syncthreads();
  if(threadIdx.x==0) bsum[blockIdx.x] = wsum[0]+wsum[1]+wsum[2]+wsum[3];
}

// phase B: exclusive scan of 196 block sums
__global__ __launch_bounds__(256) void k_midB(const int* __restrict__ bsum, int* bpre, int* offs){
  __shared__ int wsum[4];
  int t = threadIdx.x;
  int x = (t<NB)? bsum[t] : 0;
  int incl = block_scan_incl(x, wsum);
  if(t<NB) bpre[t] = incl - x;
  if(t==255) offs[NN] = incl;   // total
}

// phase C: per-block exclusive scan of cnt + bpre -> offs
__global__ __launch_bounds__(256) void k_offsC(const int* __restrict__ cnt, const int* __restrict__ bpre,
                                               int* offs){
  __shared__ int wsum[4];
  int i = blockIdx.x*256+threadIdx.x;
  int x = (i<NN)? cnt[i] : 0;
  int incl = block_scan_incl(x, wsum);
  if(i<NN) offs[i] = bpre[blockIdx.x] + incl - x;
}

// atomic-free scatter: csr[offs[c]+pos[e]] = (row, ew)
__global__ __launch_bounds__(256) void k_scatter(const int* __restrict__ ei, const float* __restrict__ ew,
                                                 const int* __restrict__ offs, const int* __restrict__ pos,
                                                 int2* __restrict__ csr){
  int e = blockIdx.x*256+threadIdx.x;
  if(e<NE){
    int c = ei[NE+e];
    int2 v; v.x = ei[e]; v.y = __float_as_int(ew[e]);
    csr[offs[c]+pos[e]] = v;
  }
}

// deg = 1 + row-sum of ew (atomic-free), dis = rsqrt(deg)  [deg>=1 always]
__global__ __launch_bounds__(256) void k_deg(const int2* __restrict__ csr, const int* __restrict__ offs,
                                             float* dis){
  int i = blockIdx.x*256+threadIdx.x;
  if(i<NN){
    float s = 1.f;
    int e0=offs[i], e1=offs[i+1];
    for(int j=e0;j<e1;j++) s += __int_as_float(csr[j].y);
    dis[i] = rsqrtf(s);
  }
}

// patch edge norm in place: y = dis[r]*ew   (dis[c] factored out in k_agg)
__global__ __launch_bounds__(256) void k_normE(int2* __restrict__ csr, const float* __restrict__ dis){
  int j = blockIdx.x*256+threadIdx.x;
  if(j<NE){
    int2 v = csr[j];
    v.y = __float_as_int(dis[v.x]*__int_as_float(v.y));
    csr[j] = v;
  }
}

// ---------------- layer-0 matmul: wave = feature slice (uniform), lane = node ----------------
// t-OUTER loop (r8 win): per-wave L1 window 4 KB vs 24 KB.
__global__ __launch_bounds__(256) void k_mm0(const float* __restrict__ X, const float* __restrict__ W,
                                             unsigned* __restrict__ A){
  int s = __builtin_amdgcn_readfirstlane(threadIdx.x>>6);   // 0..3, wave-uniform
  int n = blockIdx.x*64 + (threadIdx.x&63);
  if(n>=NN) return;
  const float* xb = X + (long long)n*64;
  const float* wb = W + 12*s;
  float acc[TT][12];
#pragma unroll
  for(int t=0;t<TT;t++)
#pragma unroll
    for(int j=0;j<12;j++) acc[t][j]=0.f;
#pragma unroll
  for(int t=0;t<TT;t++){                 // full unroll: acc[t] constant-indexed
    const float* xt = xb + (long long)t*NN*64;
#pragma unroll 2
    for(int k4=0;k4<16;k4++){
      float4 xv = *reinterpret_cast<const float4*>(xt + 4*k4);
#pragma unroll
      for(int q=0;q<4;q++){
        const float* wr = wb + (4*k4+q)*HID;
        float w[12];
#pragma unroll
        for(int j=0;j<12;j++) w[j]=wr[j];   // uniform addr -> s_load
        float xs = (&xv.x)[q];
#pragma unroll
        for(int j=0;j<12;j++) acc[t][j] = fmaf(xs, w[j], acc[t][j]);
      }
    }
  }
  unsigned buf[36];
#pragma unroll
  for(int j=0;j<12;j++){
    buf[3*j  ]=pack2(acc[0][j],acc[1][j]);
    buf[3*j+1]=pack2(acc[2][j],acc[3][j]);
    buf[3*j+2]=pack2(acc[4][j],acc[5][j]);
  }
  uint4* o4 = reinterpret_cast<uint4*>(A + (long long)n*144 + 36*s);
#pragma unroll
  for(int q=0;q<9;q++) o4[q] = make_uint4(buf[4*q],buf[4*q+1],buf[4*q+2],buf[4*q+3]);
}

// ---------------- layer-1 matmul (K=48), input fp32 [n][t][48], t-outer ----------------
__global__ __launch_bounds__(256) void k_mm1(const float* __restrict__ X, const float* __restrict__ W,
                                             unsigned* __restrict__ A){
  int s = __builtin_amdgcn_readfirstlane(threadIdx.x>>6);
  int n = blockIdx.x*64 + (threadIdx.x&63);
  if(n>=NN) return;
  const float* xb = X + (long long)n*(TT*HID);
  const float* wb = W + 12*s;
  float acc[TT][12];
#pragma unroll
  for(int t=0;t<TT;t++)
#pragma unroll
    for(int j=0;j<12;j++) acc[t][j]=0.f;
#pragma unroll
  for(int t=0;t<TT;t++){                 // full unroll: acc[t] constant-indexed
    const float* xt = xb + t*HID;
#pragma unroll 2
    for(int k4=0;k4<12;k4++){
      float4 xv = *reinterpret_cast<const float4*>(xt + 4*k4);
#pragma unroll
      for(int q=0;q<4;q++){
        const float* wr = wb + (4*k4+q)*HID;
        float w[12];
#pragma unroll
        for(int j=0;j<12;j++) w[j]=wr[j];
        float xs = (&xv.x)[q];
#pragma unroll
        for(int j=0;j<12;j++) acc[t][j] = fmaf(xs, w[j], acc[t][j]);
      }
    }
  }
  unsigned buf[36];
#pragma unroll
  for(int j=0;j<12;j++){
    buf[3*j  ]=pack2(acc[0][j],acc[1][j]);
    buf[3*j+1]=pack2(acc[2][j],acc[3][j]);
    buf[3*j+2]=pack2(acc[4][j],acc[5][j]);
  }
  uint4* o4 = reinterpret_cast<uint4*>(A + (long long)n*144 + 36*s);
#pragma unroll
  for(int q=0;q<9;q++) o4[q] = make_uint4(buf[4*q],buf[4*q+1],buf[4*q+2],buf[4*q+3]);
}

// ---------------- CSR aggregation (bf16 gather) + bias + LN + ReLU (+resid)
// edge norm stored = dis[r]*ew ; dis[c] factored: out = dn*(Σ nr*x_r + dn*x_c)
__global__ __launch_bounds__(256) void k_agg(const unsigned* __restrict__ A, const float* __restrict__ bias,
                                             const float* __restrict__ gain, const float* __restrict__ beta,
                                             const float* __restrict__ resid, float* __restrict__ out,
                                             const int* __restrict__ offs, const int2* __restrict__ csr,
                                             const float* __restrict__ dis){
  int wid = (blockIdx.x*256+threadIdx.x)>>6;
  int lane = threadIdx.x & 63;
  if(wid>=NN) return;
  const bool act = lane<HID;
  const int f = act? lane : (HID-1);
  float dn = dis[wid];
  float acc[TT];
  {
    U3 v = *reinterpret_cast<const U3*>(A + (long long)wid*144 + 3*f);
    acc[0]=dn*bflo(v.x); acc[1]=dn*bfhi(v.x);
    acc[2]=dn*bflo(v.y); acc[3]=dn*bfhi(v.y);
    acc[4]=dn*bflo(v.z); acc[5]=dn*bfhi(v.z);
  }
  int e0=offs[wid], e1=offs[wid+1];
  int e=e0;
  for(; e+3<e1; e+=4){
    int2 i0=csr[e], i1=csr[e+1], i2=csr[e+2], i3=csr[e+3];
    U3 d0 = *reinterpret_cast<const U3*>(A + (long long)i0.x*144 + 3*f);
    U3 d1 = *reinterpret_cast<const U3*>(A + (long long)i1.x*144 + 3*f);
    U3 d2 = *reinterpret_cast<const U3*>(A + (long long)i2.x*144 + 3*f);
    U3 d3 = *reinterpret_cast<const U3*>(A + (long long)i3.x*144 + 3*f);
    float n0=__int_as_float(i0.y), n1=__int_as_float(i1.y);
    float n2=__int_as_float(i2.y), n3=__int_as_float(i3.y);
    acc[0]=fmaf(n0,bflo(d0.x),acc[0]); acc[1]=fmaf(n0,bfhi(d0.x),acc[1]);
    acc[2]=fmaf(n0,bflo(d0.y),acc[2]); acc[3]=fmaf(n0,bfhi(d0.y),acc[3]);
    acc[4]=fmaf(n0,bflo(d0.z),acc[4]); acc[5]=fmaf(n0,bfhi(d0.z),acc[5]);
    acc[0]=fmaf(n1,bflo(d1.x),acc[0]); acc[1]=fmaf(n1,bfhi(d1.x),acc[1]);
    acc[2]=fmaf(n1,bflo(d1.y),acc[2]); acc[3]=fmaf(n1,bfhi(d1.y),acc[3]);
    acc[4]=fmaf(n1,bflo(d1.z),acc[4]); acc[5]=fmaf(n1,bfhi(d1.z),acc[5]);
    acc[0]=fmaf(n2,bflo(d2.x),acc[0]); acc[1]=fmaf(n2,bfhi(d2.x),acc[1]);
    acc[2]=fmaf(n2,bflo(d2.y),acc[2]); acc[3]=fmaf(n2,bfhi(d2.y),acc[3]);
    acc[4]=fmaf(n2,bflo(d2.z),acc[4]); acc[5]=fmaf(n2,bfhi(d2.z),acc[5]);
    acc[0]=fmaf(n3,bflo(d3.x),acc[0]); acc[1]=fmaf(n3,bfhi(d3.x),acc[1]);
    acc[2]=fmaf(n3,bflo(d3.y),acc[2]); acc[3]=fmaf(n3,bfhi(d3.y),acc[3]);
    acc[4]=fmaf(n3,bflo(d3.z),acc[4]); acc[5]=fmaf(n3,bfhi(d3.z),acc[5]);
  }
  for(; e<e1; ++e){
    int2 i0=csr[e];
    U3 d0 = *reinterpret_cast<const U3*>(A + (long long)i0.x*144 + 3*f);
    float n0=__int_as_float(i0.y);
    acc[0]=fmaf(n0,bflo(d0.x),acc[0]); acc[1]=fmaf(n0,bfhi(d0.x),acc[1]);
    acc[2]=fmaf(n0,bflo(d0.y),acc[2]); acc[3]=fmaf(n0,bfhi(d0.y),acc[3]);
    acc[4]=fmaf(n0,bflo(d0.z),acc[4]); acc[5]=fmaf(n0,bfhi(d0.z),acc[5]);
  }
  float bb = bias[f], gg = gain[f], be = beta[f];
  const float rn = 1.0f/HID;
#pragma unroll
  for(int t=0;t<TT;t++){
    float val = fmaf(acc[t], dn, bb);    // final *dn fold
    float v = act? val : 0.f;
    float s = v, s2 = v*v;
#pragma unroll
    for(int m=32;m>=1;m>>=1){
      s  += __shfl_xor(s,  m, 64);
      s2 += __shfl_xor(s2, m, 64);
    }
    float mu  = s*rn;
    float var = fmaxf(s2*rn - mu*mu, 0.f);
    float y = (val-mu)*rsqrtf(var+1e-5f)*gg + be;
    y = fmaxf(y, 0.f);
    long long oidx = (long long)wid*(TT*HID) + t*HID + f;
    if(resid) y += resid[oidx];
    if(act) out[oidx] = y;
  }
}

// ---------------- fused GRU v4: 12 waves, phase-split so each scalar working set is 13.8 KB/CU ----
// block: 64 nodes, 768 threads = 12 waves. Wave w owns hidden features 4w..4w+3 (12 gate rows).
// Two 3-step super-phases: {phase 1: gi for t..t+2 into 18 fp16-pair regs (x-weights stream once);
// phase 2: 3 recurrence steps whose 13.8 KB h-weight set is scalar-cache-resident}.
// k-loop = proven r5 shape narrowed: ws[12] s_load + 1 ds_read + 12 dot2, unroll 2.
__global__ __launch_bounds__(768) void k_gruF4(const float* __restrict__ X,   // h2 [n][t][48]
                                               const unsigned* __restrict__ W2, // [12][24][24] u32
                                               const float* __restrict__ bih, const float* __restrict__ bhh,
                                               const float* __restrict__ Wc1, const float* __restrict__ bc1,
                                               const float* __restrict__ Wc2, const float* __restrict__ bc2,
                                               float* __restrict__ out){
  __shared__ unsigned xall[TT*24*64];   // 36 KB
  __shared__ unsigned hb[2][24*64];     // 12 KB
  int tid = threadIdx.x;
  int wv = __builtin_amdgcn_readfirstlane(tid>>6);   // 0..11, uniform
  int lane = tid & 63;
  int f0 = wv*4;
  long long n = (long long)blockIdx.x*64 + lane;

  // stage x: thread (nd,q) loads node nd's float4 chunk q for all 6 t
  {
    int nd = tid/12, q = tid-12*nd;
    long long g = (long long)blockIdx.x*64+nd; if(g>NN-1) g=NN-1;
    const float* xs = X + g*(TT*HID) + 4*q;
#pragma unroll
    for(int t=0;t<TT;t++){
      float4 v = *reinterpret_cast<const float4*>(xs + t*HID);
      xall[(t*24 + 2*q  )*64 + nd] = pkrtz(v.x, v.y);
      xall[(t*24 + 2*q+1)*64 + nd] = pkrtz(v.z, v.w);
    }
  }
  for(int i=tid;i<24*64;i+=768) hb[0][i]=0u;

  float rbi[4], zbi[4], nbi[4], rbh[4], zbh[4], nbh[4], hprev[4];
#pragma unroll
  for(int j=0;j<4;j++){
    rbi[j]=bih[f0+j]; zbi[j]=bih[48+f0+j]; nbi[j]=bih[96+f0+j];
    rbh[j]=bhh[f0+j]; zbh[j]=bhh[48+f0+j]; nbh[j]=bhh[96+f0+j];
    hprev[j]=0.f;
  }
  __syncthreads();   // xall + hb[0] ready

  int cur=0;
#pragma unroll
  for(int tp=0; tp<2; tp++){
    // ---- phase 1: gi for steps 3tp..3tp+2 (x-side only, barrier-free) ----
    unsigned gi[18];
#pragma unroll
    for(int s=0;s<3;s++){
      float a[12];
#pragma unroll
      for(int j=0;j<4;j++){ a[j]=rbi[j]; a[4+j]=zbi[j]; a[8+j]=nbi[j]; }
      const unsigned* xtc = &xall[(tp*3+s)*24*64];
#pragma unroll 2
      for(int k2=0;k2<24;k2++){
        const unsigned* wp = W2 + (wv*24+k2)*24 + 12;   // x-slice
        unsigned ws[12];
#pragma unroll
        for(int q=0;q<12;q++) ws[q]=wp[q];              // uniform -> s_load
        unsigned xk = xtc[k2*64+lane];
#pragma unroll
        for(int c=0;c<12;c++) a[c]=dot2f(xk, ws[c], a[c]);
      }
#pragma unroll
      for(int m=0;m<6;m++) gi[s*6+m]=pack2h(a[2*m], a[2*m+1]);
    }
    // ---- phase 2: 3 recurrence steps (h-weights sK$-resident) ----
#pragma unroll
    for(int s=0;s<3;s++){
      float acc[12];
#pragma unroll
      for(int j=0;j<4;j++){ acc[j]=rbh[j]; acc[4+j]=zbh[j]; acc[8+j]=nbh[j]; }
      const unsigned* hbc = &hb[cur][0];
#pragma unroll 2
      for(int k2=0;k2<24;k2++){
        const unsigned* wp = W2 + (wv*24+k2)*24;        // h-slice
        unsigned ws[12];
#pragma unroll
        for(int q=0;q<12;q++) ws[q]=wp[q];              // uniform -> s_load
        unsigned h2k = hbc[k2*64+lane];
#pragma unroll
        for(int c=0;c<12;c++) acc[c]=dot2f(h2k, ws[c], acc[c]);
      }
      unsigned* hw = &hb[cur^1][0];
      float hn[4];
#pragma unroll
      for(int j=0;j<4;j++){
        unsigned pr=gi[s*6+(j>>1)], pz=gi[s*6+2+(j>>1)], pn=gi[s*6+4+(j>>1)];
        float gir=(j&1)? h2f(pr>>16):h2f(pr);
        float giz=(j&1)? h2f(pz>>16):h2f(pz);
        float gin=(j&1)? h2f(pn>>16):h2f(pn);
        float r  = sigmoidf_(acc[j]+gir);
        float zg = sigmoidf_(acc[4+j]+giz);
        float ng = tanhf_(gin + r*acc[8+j]);
        float hv = (1.f-zg)*ng + zg*hprev[j];
        hprev[j]=hv; hn[j]=hv;
      }
      hw[(2*wv  )*64+lane] = pack2h(hn[0],hn[1]);
      hw[(2*wv+1)*64+lane] = pack2h(hn[2],hn[3]);
      __syncthreads();   // next buffer fully written
      cur^=1;
    }
  }

  // classifier epilogue: wave 0 covers the block's 64 nodes
  if(wv==0 && n<NN){
    const unsigned* hbc=&hb[cur][0];
    float hv[24];
#pragma unroll
    for(int j=0;j<24;j++) hv[j]=bc1[j];
#pragma unroll 2
    for(int k2=0;k2<24;k2++){
      unsigned u = hbc[k2*64+lane];
      float hk0 = h2f(u), hk1 = h2f(u>>16);
      const float* w0 = Wc1 + (2*k2)*24;     // uniform -> s_load
      const float* w1 = Wc1 + (2*k2+1)*24;
#pragma unroll
      for(int j=0;j<24;j++) hv[j] = fmaf(hk0, w0[j], hv[j]);
#pragma unroll
      for(int j=0;j<24;j++) hv[j] = fmaf(hk1, w1[j], hv[j]);
    }
    float l0=bc2[0], l1=bc2[1];
#pragma unroll
    for(int j=0;j<24;j++){
      float a = fmaxf(hv[j],0.f);
      l0 = fmaf(a, Wc2[2*j],   l0);
      l1 = fmaf(a, Wc2[2*j+1], l1);
    }
    reinterpret_cast<float2*>(out)[n] = make_float2(l0,l1);
  }
}

static inline size_t al256(size_t x){ return (x+255)&~(size_t)255; }

extern "C" void kernel_launch(void* const* d_in, const int* in_sizes, int n_in,
                              void* d_out, int out_size, void* d_ws, size_t ws_size,
                              hipStream_t stream){
  const float* x_seq=(const float*)d_in[0];
  const int*   ei   =(const int*)d_in[1];
  const float* ew   =(const float*)d_in[2];
  const float* W0=(const float*)d_in[3];  const float* b0=(const float*)d_in[4];
  const float* g0=(const float*)d_in[5];  const float* be0=(const float*)d_in[6];
  const float* W1=(const float*)d_in[7];  const float* b1=(const float*)d_in[8];
  const float* g1=(const float*)d_in[9];  const float* be1=(const float*)d_in[10];
  const float* Wih=(const float*)d_in[11];const float* Whh=(const float*)d_in[12];
  const float* bih=(const float*)d_in[13];const float* bhh=(const float*)d_in[14];
  const float* Wc1=(const float*)d_in[15];const float* bc1=(const float*)d_in[16];
  const float* Wc2=(const float*)d_in[17];const float* bc2=(const float*)d_in[18];
  float* outp=(float*)d_out;

  char* p=(char*)d_ws; size_t off=0;
  auto alloc=[&](size_t bytes)->void*{ void* r=p+off; off=al256(off+bytes); return r; };
  float* dis    =(float*)alloc((size_t)NN*4);
  int*   cnt    =(int*)  alloc((size_t)NN*4);
  int*   offs   =(int*)  alloc((size_t)(NN+1)*4);
  int*   bsum   =(int*)  alloc((size_t)NB*4);
  int*   bpre   =(int*)  alloc((size_t)NB*4);
  int*   pos    =(int*)  alloc((size_t)NE*4);
  int2*  csr    =(int2*) alloc((size_t)NE*8);
  unsigned* W2  =(unsigned*)alloc((size_t)12*24*24*4);
  unsigned* A   =(unsigned*)alloc((size_t)NN*576 + 1024);   // bf16 [n][f][t6], 576B/row
  float* h1     =(float*)alloc((size_t)NN*TT*HID*4);
  float* h2     =(float*)alloc((size_t)NN*TT*HID*4);

  const int GN=(NN+255)/256, GE=(NE+255)/256;
  const int GMM=(NN+63)/64;              // 64 nodes/block
  const int GAGG=(NN*64+255)/256;        // 1 wave/node
  const int GGRU=(NN+63)/64;             // 64 nodes/block, 12 waves

  k_setup  <<<GN,256,0,stream>>>(cnt,Wih,Whh,W2);
  k_cnt    <<<GE,256,0,stream>>>(ei,cnt,pos);
  k_partA  <<<NB,256,0,stream>>>(cnt,bsum);
  k_midB   <<<1,256,0,stream>>>(bsum,bpre,offs);
  k_offsC  <<<NB,256,0,stream>>>(cnt,bpre,offs);
  k_scatter<<<GE,256,0,stream>>>(ei,ew,offs,pos,csr);
  k_deg    <<<GN,256,0,stream>>>(csr,offs,dis);
  k_normE  <<<GE,256,0,stream>>>(csr,dis);

  // layer 0
  k_mm0<<<GMM,256,0,stream>>>(x_seq, W0, A);
  k_agg<<<GAGG,256,0,stream>>>(A,b0,g0,be0,nullptr,h1,offs,csr,dis);
  // layer 1 (residual = h1)
  k_mm1<<<GMM,256,0,stream>>>(h1, W1, A);
  k_agg<<<GAGG,256,0,stream>>>(A,b1,g1,be1,h1,h2,offs,csr,dis);
  // fused GRU v4 (12-wave phase-split) + classifier
  k_gruF4<<<GGRU,768,0,stream>>>(h2, W2, bih,bhh, Wc1,bc1,Wc2,bc2, outp);
}

// Round 10
// 605.908 us; speedup vs baseline: 1.2000x; 1.0134x over previous
//
#include <hip/hip_runtime.h>
#include <hip/hip_fp16.h>
#include <math.h>

#define NN 50000
#define NE 800000
#define TT 6
#define HID 48
#define NB 196   // (NN+255)/256
#define XS 28    // node-major LDS row stride in u32 (112B, 16B-aligned, (7*lane+c)%8 quad-conflict-free)

__device__ __forceinline__ float sigmoidf_(float x){ return 1.0f/(1.0f+__expf(-x)); }
__device__ __forceinline__ float tanhf_(float x){
  float xc = fminf(fmaxf(x,-15.f),15.f);
  float t = __expf(2.f*xc);
  return (t-1.f)/(t+1.f);
}
__device__ __forceinline__ unsigned f2bf(float x){
  unsigned u = __float_as_uint(x);
  return (u + 0x7fffu + ((u>>16)&1u)) >> 16;   // RNE to bf16
}
__device__ __forceinline__ unsigned pack2(float a, float b){
  return f2bf(a) | (f2bf(b)<<16);
}
__device__ __forceinline__ float bflo(unsigned u){ return __uint_as_float(u<<16); }
__device__ __forceinline__ float bfhi(unsigned u){ return __uint_as_float(u & 0xffff0000u); }
__device__ __forceinline__ unsigned f2h(float x){
  return (unsigned)__half_as_ushort(__float2half(x));   // RNE fp16
}
__device__ __forceinline__ float h2f(unsigned u){
  return __half2float(__ushort_as_half((unsigned short)(u & 0xffffu)));
}
__device__ __forceinline__ unsigned pack2h(float a, float b){   // RNE fp16 pair
  return f2h(a) | (f2h(b)<<16);
}

typedef __fp16 h2t __attribute__((ext_vector_type(2)));

__device__ __forceinline__ unsigned pkrtz(float a, float b){    // fast packed cvt (RTZ)
#if __has_builtin(__builtin_amdgcn_cvt_pkrtz)
  auto r = __builtin_amdgcn_cvt_pkrtz(a, b);
  return __builtin_bit_cast(unsigned, r);
#else
  return pack2h(a, b);
#endif
}
// acc += lo(a)*lo(b) + hi(a)*hi(b), fp32 accumulate
__device__ __forceinline__ float dot2f(unsigned a, unsigned b, float c){
#if __has_builtin(__builtin_amdgcn_fdot2)
  return __builtin_amdgcn_fdot2(__builtin_bit_cast(h2t, a), __builtin_bit_cast(h2t, b), c, false);
#else
  h2t av = __builtin_bit_cast(h2t, a), bv = __builtin_bit_cast(h2t, b);
  return c + (float)av[0]*(float)bv[0] + (float)av[1]*(float)bv[1];
#endif
}

struct U3 { unsigned x,y,z; };

// 256-thread inclusive block scan (4 waves of 64)
__device__ __forceinline__ int block_scan_incl(int x, int* wsum){
  int lane = threadIdx.x & 63, w = threadIdx.x >> 6;
  int v = x;
#pragma unroll
  for(int d=1; d<64; d<<=1){
    int u = __shfl_up(v, d, 64);
    if(lane >= d) v += u;
  }
  if(lane==63) wsum[w] = v;
  __syncthreads();
  int add = 0;
#pragma unroll
  for(int k=0;k<3;k++) if(w>k) add += wsum[k];
  return v + add;
}

// ---------------- setup: cnt init + GRU weight repack (fp16 pairs along k) ----------------
// W2 [12 w][24 k2][24 c] u32: wave w owns hidden features 4w..4w+3.
//   c<12 : h-side (Whh), cc=c:   cc<4 -> r-row (4w+cc), cc<8 -> z-row (48+4w+cc-4), else n-row (96+4w+cc-8)
//   c>=12: x-side (Wih), cc=c-12, same row map.
__global__ __launch_bounds__(256) void k_setup(int* cnt,
                                               const float* __restrict__ Wih, const float* __restrict__ Whh,
                                               unsigned* W2){
  int i = blockIdx.x*256+threadIdx.x;
  if(i<NN) cnt[i]=0;
  if(i < 12*24*24){
    int w = i/576, r = i%576;
    int k2 = r/24, c = r%24;
    int cc = (c<12)? c : (c-12);
    int row = (cc<4) ? (w*4 + cc) : (cc<8) ? (48 + w*4 + cc-4) : (96 + w*4 + cc-8);
    const float* Wsrc = (c<12)? Whh : Wih;
    W2[i] = pack2h(Wsrc[row*48 + 2*k2], Wsrc[row*48 + 2*k2 + 1]);
  }
}

// single atomic per edge: rank within destination bucket
__global__ __launch_bounds__(256) void k_cnt(const int* __restrict__ ei, int* cnt, int* pos){
  int e = blockIdx.x*256+threadIdx.x;
  if(e<NE){
    int c = ei[NE+e];
    pos[e] = atomicAdd(&cnt[c], 1);
  }
}

// phase A: per-block sums of cnt
__global__ __launch_bounds__(256) void k_partA(const int* __restrict__ cnt, int* bsum){
  __shared__ int wsum[4];
  int i = blockIdx.x*256+threadIdx.x;
  int x = (i<NN)? cnt[i] : 0;
  int lane = threadIdx.x & 63, w = threadIdx.x >> 6;
  int v = x;
#pragma unroll
  for(int m=32;m>=1;m>>=1) v += __shfl_xor(v, m, 64);
  if(lane==0) wsum[w]=v;
  __syncthreads();
  if(threadIdx.x==0) bsum[blockIdx.x] = wsum[0]+wsum[1]+wsum[2]+wsum[3];
}

// phase B: exclusive scan of 196 block sums
__global__ __launch_bounds__(256) void k_midB(const int* __restrict__ bsum, int* bpre, int* offs){
  __shared__ int wsum[4];
  int t = threadIdx.x;
  int x = (t<NB)? bsum[t] : 0;
  int incl = block_scan_incl(x, wsum);
  if(t<NB) bpre[t] = incl - x;
  if(t==255) offs[NN] = incl;   // total
}

// phase C: per-block exclusive scan of cnt + bpre -> offs
__global__ __launch_bounds__(256) void k_offsC(const int* __restrict__ cnt, const int* __restrict__ bpre,
                                               int* offs){
  __shared__ int wsum[4];
  int i = blockIdx.x*256+threadIdx.x;
  int x = (i<NN)? cnt[i] : 0;
  int incl = block_scan_incl(x, wsum);
  if(i<NN) offs[i] = bpre[blockIdx.x] + incl - x;
}

// atomic-free scatter: csr[offs[c]+pos[e]] = (row, ew)
__global__ __launch_bounds__(256) void k_scatter(const int* __restrict__ ei, const float* __restrict__ ew,
                                                 const int* __restrict__ offs, const int* __restrict__ pos,
                                                 int2* __restrict__ csr){
  int e = blockIdx.x*256+threadIdx.x;
  if(e<NE){
    int c = ei[NE+e];
    int2 v; v.x = ei[e]; v.y = __float_as_int(ew[e]);
    csr[offs[c]+pos[e]] = v;
  }
}

// deg = 1 + row-sum of ew (atomic-free), dis = rsqrt(deg)  [deg>=1 always]
__global__ __launch_bounds__(256) void k_deg(const int2* __restrict__ csr, const int* __restrict__ offs,
                                             float* dis){
  int i = blockIdx.x*256+threadIdx.x;
  if(i<NN){
    float s = 1.f;
    int e0=offs[i], e1=offs[i+1];
    for(int j=e0;j<e1;j++) s += __int_as_float(csr[j].y);
    dis[i] = rsqrtf(s);
  }
}

// patch edge norm in place: y = dis[r]*ew   (dis[c] factored out in k_agg)
__global__ __launch_bounds__(256) void k_normE(int2* __restrict__ csr, const float* __restrict__ dis){
  int j = blockIdx.x*256+threadIdx.x;
  if(j<NE){
    int2 v = csr[j];
    v.y = __float_as_int(dis[v.x]*__int_as_float(v.y));
    csr[j] = v;
  }
}

// ---------------- layer-0 matmul: wave = feature slice (uniform), lane = node ----------------
// t-OUTER loop (r8 win): per-wave L1 window 4 KB vs 24 KB.
__global__ __launch_bounds__(256) void k_mm0(const float* __restrict__ X, const float* __restrict__ W,
                                             unsigned* __restrict__ A){
  int s = __builtin_amdgcn_readfirstlane(threadIdx.x>>6);   // 0..3, wave-uniform
  int n = blockIdx.x*64 + (threadIdx.x&63);
  if(n>=NN) return;
  const float* xb = X + (long long)n*64;
  const float* wb = W + 12*s;
  float acc[TT][12];
#pragma unroll
  for(int t=0;t<TT;t++)
#pragma unroll
    for(int j=0;j<12;j++) acc[t][j]=0.f;
#pragma unroll
  for(int t=0;t<TT;t++){                 // full unroll: acc[t] constant-indexed
    const float* xt = xb + (long long)t*NN*64;
#pragma unroll 2
    for(int k4=0;k4<16;k4++){
      float4 xv = *reinterpret_cast<const float4*>(xt + 4*k4);
#pragma unroll
      for(int q=0;q<4;q++){
        const float* wr = wb + (4*k4+q)*HID;
        float w[12];
#pragma unroll
        for(int j=0;j<12;j++) w[j]=wr[j];   // uniform addr -> s_load
        float xs = (&xv.x)[q];
#pragma unroll
        for(int j=0;j<12;j++) acc[t][j] = fmaf(xs, w[j], acc[t][j]);
      }
    }
  }
  unsigned buf[36];
#pragma unroll
  for(int j=0;j<12;j++){
    buf[3*j  ]=pack2(acc[0][j],acc[1][j]);
    buf[3*j+1]=pack2(acc[2][j],acc[3][j]);
    buf[3*j+2]=pack2(acc[4][j],acc[5][j]);
  }
  uint4* o4 = reinterpret_cast<uint4*>(A + (long long)n*144 + 36*s);
#pragma unroll
  for(int q=0;q<9;q++) o4[q] = make_uint4(buf[4*q],buf[4*q+1],buf[4*q+2],buf[4*q+3]);
}

// ---------------- layer-1 matmul (K=48), input fp32 [n][t][48], t-outer ----------------
__global__ __launch_bounds__(256) void k_mm1(const float* __restrict__ X, const float* __restrict__ W,
                                             unsigned* __restrict__ A){
  int s = __builtin_amdgcn_readfirstlane(threadIdx.x>>6);
  int n = blockIdx.x*64 + (threadIdx.x&63);
  if(n>=NN) return;
  const float* xb = X + (long long)n*(TT*HID);
  const float* wb = W + 12*s;
  float acc[TT][12];
#pragma unroll
  for(int t=0;t<TT;t++)
#pragma unroll
    for(int j=0;j<12;j++) acc[t][j]=0.f;
#pragma unroll
  for(int t=0;t<TT;t++){                 // full unroll: acc[t] constant-indexed
    const float* xt = xb + t*HID;
#pragma unroll 2
    for(int k4=0;k4<12;k4++){
      float4 xv = *reinterpret_cast<const float4*>(xt + 4*k4);
#pragma unroll
      for(int q=0;q<4;q++){
        const float* wr = wb + (4*k4+q)*HID;
        float w[12];
#pragma unroll
        for(int j=0;j<12;j++) w[j]=wr[j];
        float xs = (&xv.x)[q];
#pragma unroll
        for(int j=0;j<12;j++) acc[t][j] = fmaf(xs, w[j], acc[t][j]);
      }
    }
  }
  unsigned buf[36];
#pragma unroll
  for(int j=0;j<12;j++){
    buf[3*j  ]=pack2(acc[0][j],acc[1][j]);
    buf[3*j+1]=pack2(acc[2][j],acc[3][j]);
    buf[3*j+2]=pack2(acc[4][j],acc[5][j]);
  }
  uint4* o4 = reinterpret_cast<uint4*>(A + (long long)n*144 + 36*s);
#pragma unroll
  for(int q=0;q<9;q++) o4[q] = make_uint4(buf[4*q],buf[4*q+1],buf[4*q+2],buf[4*q+3]);
}

// ---------------- CSR aggregation (bf16 gather) + bias + LN + ReLU (+resid)
// edge norm stored = dis[r]*ew ; dis[c] factored: out = dn*(Σ nr*x_r + dn*x_c)
__global__ __launch_bounds__(256) void k_agg(const unsigned* __restrict__ A, const float* __restrict__ bias,
                                             const float* __restrict__ gain, const float* __restrict__ beta,
                                             const float* __restrict__ resid, float* __restrict__ out,
                                             const int* __restrict__ offs, const int2* __restrict__ csr,
                                             const float* __restrict__ dis){
  int wid = (blockIdx.x*256+threadIdx.x)>>6;
  int lane = threadIdx.x & 63;
  if(wid>=NN) return;
  const bool act = lane<HID;
  const int f = act? lane : (HID-1);
  float dn = dis[wid];
  float acc[TT];
  {
    U3 v = *reinterpret_cast<const U3*>(A + (long long)wid*144 + 3*f);
    acc[0]=dn*bflo(v.x); acc[1]=dn*bfhi(v.x);
    acc[2]=dn*bflo(v.y); acc[3]=dn*bfhi(v.y);
    acc[4]=dn*bflo(v.z); acc[5]=dn*bfhi(v.z);
  }
  int e0=offs[wid], e1=offs[wid+1];
  int e=e0;
  for(; e+3<e1; e+=4){
    int2 i0=csr[e], i1=csr[e+1], i2=csr[e+2], i3=csr[e+3];
    U3 d0 = *reinterpret_cast<const U3*>(A + (long long)i0.x*144 + 3*f);
    U3 d1 = *reinterpret_cast<const U3*>(A + (long long)i1.x*144 + 3*f);
    U3 d2 = *reinterpret_cast<const U3*>(A + (long long)i2.x*144 + 3*f);
    U3 d3 = *reinterpret_cast<const U3*>(A + (long long)i3.x*144 + 3*f);
    float n0=__int_as_float(i0.y), n1=__int_as_float(i1.y);
    float n2=__int_as_float(i2.y), n3=__int_as_float(i3.y);
    acc[0]=fmaf(n0,bflo(d0.x),acc[0]); acc[1]=fmaf(n0,bfhi(d0.x),acc[1]);
    acc[2]=fmaf(n0,bflo(d0.y),acc[2]); acc[3]=fmaf(n0,bfhi(d0.y),acc[3]);
    acc[4]=fmaf(n0,bflo(d0.z),acc[4]); acc[5]=fmaf(n0,bfhi(d0.z),acc[5]);
    acc[0]=fmaf(n1,bflo(d1.x),acc[0]); acc[1]=fmaf(n1,bfhi(d1.x),acc[1]);
    acc[2]=fmaf(n1,bflo(d1.y),acc[2]); acc[3]=fmaf(n1,bfhi(d1.y),acc[3]);
    acc[4]=fmaf(n1,bflo(d1.z),acc[4]); acc[5]=fmaf(n1,bfhi(d1.z),acc[5]);
    acc[0]=fmaf(n2,bflo(d2.x),acc[0]); acc[1]=fmaf(n2,bfhi(d2.x),acc[1]);
    acc[2]=fmaf(n2,bflo(d2.y),acc[2]); acc[3]=fmaf(n2,bfhi(d2.y),acc[3]);
    acc[4]=fmaf(n2,bflo(d2.z),acc[4]); acc[5]=fmaf(n2,bfhi(d2.z),acc[5]);
    acc[0]=fmaf(n3,bflo(d3.x),acc[0]); acc[1]=fmaf(n3,bfhi(d3.x),acc[1]);
    acc[2]=fmaf(n3,bflo(d3.y),acc[2]); acc[3]=fmaf(n3,bfhi(d3.y),acc[3]);
    acc[4]=fmaf(n3,bflo(d3.z),acc[4]); acc[5]=fmaf(n3,bfhi(d3.z),acc[5]);
  }
  for(; e<e1; ++e){
    int2 i0=csr[e];
    U3 d0 = *reinterpret_cast<const U3*>(A + (long long)i0.x*144 + 3*f);
    float n0=__int_as_float(i0.y);
    acc[0]=fmaf(n0,bflo(d0.x),acc[0]); acc[1]=fmaf(n0,bfhi(d0.x),acc[1]);
    acc[2]=fmaf(n0,bflo(d0.y),acc[2]); acc[3]=fmaf(n0,bfhi(d0.y),acc[3]);
    acc[4]=fmaf(n0,bflo(d0.z),acc[4]); acc[5]=fmaf(n0,bfhi(d0.z),acc[5]);
  }
  float bb = bias[f], gg = gain[f], be = beta[f];
  const float rn = 1.0f/HID;
#pragma unroll
  for(int t=0;t<TT;t++){
    float val = fmaf(acc[t], dn, bb);    // final *dn fold
    float v = act? val : 0.f;
    float s = v, s2 = v*v;
#pragma unroll
    for(int m=32;m>=1;m>>=1){
      s  += __shfl_xor(s,  m, 64);
      s2 += __shfl_xor(s2, m, 64);
    }
    float mu  = s*rn;
    float var = fmaxf(s2*rn - mu*mu, 0.f);
    float y = (val-mu)*rsqrtf(var+1e-5f)*gg + be;
    y = fmaxf(y, 0.f);
    long long oidx = (long long)wid*(TT*HID) + t*HID + f;
    if(resid) y += resid[oidx];
    if(act) out[oidx] = y;
  }
}

// ---------------- fused GRU v5: node-major LDS rows + pure-SMEM k-loops ----------------
// block: 64 nodes, 768 threads = 12 waves. Wave w owns hidden features 4w..4w+3 (12 gate rows).
// x/h stored NODE-MAJOR: row = 28 u32 (112B, 16B-aligned). Per step each lane reads its
// whole row via 6 ds_read_b128 (quad-bank (7*lane+c)%8 -> conflict-free), then the k-loop
// is chunks of {4 named values x (ws[12] s_load + 12 dot2)} — no ds_read inside, so the
// scalar weight stream never serializes against lgkmcnt-mixing (r3 defect eliminated),
// and the r9 staging bank conflicts (2.47M) are gone.
__global__ __launch_bounds__(768) void k_gruF5(const float* __restrict__ X,   // h2 [n][t][48]
                                               const unsigned* __restrict__ W2, // [12][24][24] u32
                                               const float* __restrict__ bih, const float* __restrict__ bhh,
                                               const float* __restrict__ Wc1, const float* __restrict__ bc1,
                                               const float* __restrict__ Wc2, const float* __restrict__ bc2,
                                               float* __restrict__ out){
  __shared__ __align__(16) unsigned xall[TT*64*XS];   // 42 KB
  __shared__ __align__(16) unsigned hb[2][64*XS];     // 14 KB
  int tid = threadIdx.x;
  int wv = __builtin_amdgcn_readfirstlane(tid>>6);   // 0..11, uniform
  int lane = tid & 63;
  int f0 = wv*4;
  long long n = (long long)blockIdx.x*64 + lane;

  // stage x: thread (nd,q) loads node nd's float4 chunk q for all 6 t; writes uint2 at
  // pair-bank (nd*14+q)%16 — ~2-way (free).
  {
    int nd = tid/12, q = tid-12*nd;
    long long g = (long long)blockIdx.x*64+nd; if(g>NN-1) g=NN-1;
    const float* xs = X + g*(TT*HID) + 4*q;
#pragma unroll
    for(int t=0;t<TT;t++){
      float4 v = *reinterpret_cast<const float4*>(xs + t*HID);
      *reinterpret_cast<uint2*>(&xall[t*64*XS + nd*XS + 2*q]) =
          make_uint2(pkrtz(v.x,v.y), pkrtz(v.z,v.w));
    }
  }
  for(int i=tid;i<64*XS;i+=768) hb[0][i]=0u;

  float rbi[4], zbi[4], nbi[4], rbh[4], zbh[4], nbh[4], hprev[4];
#pragma unroll
  for(int j=0;j<4;j++){
    rbi[j]=bih[f0+j]; zbi[j]=bih[48+f0+j]; nbi[j]=bih[96+f0+j];
    rbh[j]=bhh[f0+j]; zbh[j]=bhh[48+f0+j]; nbh[j]=bhh[96+f0+j];
    hprev[j]=0.f;
  }
  __syncthreads();   // xall + hb[0] ready

  int cur=0;
#pragma unroll
  for(int tp=0; tp<2; tp++){
    // ---- phase 1: gi for steps 3tp..3tp+2 (x-side only, barrier-free) ----
    unsigned gi[18];
#pragma unroll
    for(int s=0;s<3;s++){
      float a[12];
#pragma unroll
      for(int j=0;j<4;j++){ a[j]=rbi[j]; a[4+j]=zbi[j]; a[8+j]=nbi[j]; }
      const uint4* xrow = reinterpret_cast<const uint4*>(&xall[(tp*3+s)*64*XS + lane*XS]);
      const unsigned* wbx = W2 + wv*24*24 + 12;   // x-slice base
#pragma unroll 2
      for(int c6=0;c6<6;c6++){
        uint4 hq = xrow[c6];                      // ds_read_b128, conflict-free
        unsigned xv_[4] = {hq.x, hq.y, hq.z, hq.w};
#pragma unroll
        for(int j4=0;j4<4;j4++){
          const unsigned* wp = wbx + (4*c6+j4)*24;
          unsigned ws[12];
#pragma unroll
          for(int q=0;q<12;q++) ws[q]=wp[q];      // uniform -> s_load
#pragma unroll
          for(int c=0;c<12;c++) a[c]=dot2f(xv_[j4], ws[c], a[c]);
        }
      }
#pragma unroll
      for(int m=0;m<6;m++) gi[s*6+m]=pack2h(a[2*m], a[2*m+1]);
    }
    // ---- phase 2: 3 recurrence steps (h-weights sK$-resident, pure-SMEM k-loop) ----
#pragma unroll
    for(int s=0;s<3;s++){
      float acc[12];
#pragma unroll
      for(int j=0;j<4;j++){ acc[j]=rbh[j]; acc[4+j]=zbh[j]; acc[8+j]=nbh[j]; }
      const uint4* hrow = reinterpret_cast<const uint4*>(&hb[cur][lane*XS]);
      const unsigned* wbh = W2 + wv*24*24;        // h-slice base
#pragma unroll 2
      for(int c6=0;c6<6;c6++){
        uint4 hq = hrow[c6];                      // ds_read_b128, conflict-free
        unsigned hv_[4] = {hq.x, hq.y, hq.z, hq.w};
#pragma unroll
        for(int j4=0;j4<4;j4++){
          const unsigned* wp = wbh + (4*c6+j4)*24;
          unsigned ws[12];
#pragma unroll
          for(int q=0;q<12;q++) ws[q]=wp[q];      // uniform -> s_load
#pragma unroll
          for(int c=0;c<12;c++) acc[c]=dot2f(hv_[j4], ws[c], acc[c]);
        }
      }
      float hn[4];
#pragma unroll
      for(int j=0;j<4;j++){
        unsigned pr=gi[s*6+(j>>1)], pz=gi[s*6+2+(j>>1)], pn=gi[s*6+4+(j>>1)];
        float gir=(j&1)? h2f(pr>>16):h2f(pr);
        float giz=(j&1)? h2f(pz>>16):h2f(pz);
        float gin=(j&1)? h2f(pn>>16):h2f(pn);
        float r  = sigmoidf_(acc[j]+gir);
        float zg = sigmoidf_(acc[4+j]+giz);
        float ng = tanhf_(gin + r*acc[8+j]);
        float hv = (1.f-zg)*ng + zg*hprev[j];
        hprev[j]=hv; hn[j]=hv;
      }
      // one uint2 write per lane: words lane*XS + 2wv (+1); 8B-aligned; ~8-way pair-bank
      // on a single op per step — negligible (m136: 8-way = 2.9x on that op only).
      *reinterpret_cast<uint2*>(&hb[cur^1][lane*XS + 2*wv]) =
          make_uint2(pack2h(hn[0],hn[1]), pack2h(hn[2],hn[3]));
      __syncthreads();   // next buffer fully written
      cur^=1;
    }
  }

  // classifier epilogue: wave 0 covers the block's 64 nodes
  if(wv==0 && n<NN){
    unsigned hh[24];
    {
      const uint4* hrow = reinterpret_cast<const uint4*>(&hb[cur][lane*XS]);
#pragma unroll
      for(int c6=0;c6<6;c6++){
        uint4 v = hrow[c6];
        hh[4*c6]=v.x; hh[4*c6+1]=v.y; hh[4*c6+2]=v.z; hh[4*c6+3]=v.w;
      }
    }
    float hv[24];
#pragma unroll
    for(int j=0;j<24;j++) hv[j]=bc1[j];
#pragma unroll 2
    for(int k2=0;k2<24;k2++){
      float hk0 = h2f(hh[k2]), hk1 = h2f(hh[k2]>>16);
      const float* w0 = Wc1 + (2*k2)*24;     // uniform -> s_load
      const float* w1 = Wc1 + (2*k2+1)*24;
#pragma unroll
      for(int j=0;j<24;j++) hv[j] = fmaf(hk0, w0[j], hv[j]);
#pragma unroll
      for(int j=0;j<24;j++) hv[j] = fmaf(hk1, w1[j], hv[j]);
    }
    float l0=bc2[0], l1=bc2[1];
#pragma unroll
    for(int j=0;j<24;j++){
      float a = fmaxf(hv[j],0.f);
      l0 = fmaf(a, Wc2[2*j],   l0);
      l1 = fmaf(a, Wc2[2*j+1], l1);
    }
    reinterpret_cast<float2*>(out)[n] = make_float2(l0,l1);
  }
}

static inline size_t al256(size_t x){ return (x+255)&~(size_t)255; }

extern "C" void kernel_launch(void* const* d_in, const int* in_sizes, int n_in,
                              void* d_out, int out_size, void* d_ws, size_t ws_size,
                              hipStream_t stream){
  const float* x_seq=(const float*)d_in[0];
  const int*   ei   =(const int*)d_in[1];
  const float* ew   =(const float*)d_in[2];
  const float* W0=(const float*)d_in[3];  const float* b0=(const float*)d_in[4];
  const float* g0=(const float*)d_in[5];  const float* be0=(const float*)d_in[6];
  const float* W1=(const float*)d_in[7];  const float* b1=(const float*)d_in[8];
  const float* g1=(const float*)d_in[9];  const float* be1=(const float*)d_in[10];
  const float* Wih=(const float*)d_in[11];const float* Whh=(const float*)d_in[12];
  const float* bih=(const float*)d_in[13];const float* bhh=(const float*)d_in[14];
  const float* Wc1=(const float*)d_in[15];const float* bc1=(const float*)d_in[16];
  const float* Wc2=(const float*)d_in[17];const float* bc2=(const float*)d_in[18];
  float* outp=(float*)d_out;

  char* p=(char*)d_ws; size_t off=0;
  auto alloc=[&](size_t bytes)->void*{ void* r=p+off; off=al256(off+bytes); return r; };
  float* dis    =(float*)alloc((size_t)NN*4);
  int*   cnt    =(int*)  alloc((size_t)NN*4);
  int*   offs   =(int*)  alloc((size_t)(NN+1)*4);
  int*   bsum   =(int*)  alloc((size_t)NB*4);
  int*   bpre   =(int*)  alloc((size_t)NB*4);
  int*   pos    =(int*)  alloc((size_t)NE*4);
  int2*  csr    =(int2*) alloc((size_t)NE*8);
  unsigned* W2  =(unsigned*)alloc((size_t)12*24*24*4);
  unsigned* A   =(unsigned*)alloc((size_t)NN*576 + 1024);   // bf16 [n][f][t6], 576B/row
  float* h1     =(float*)alloc((size_t)NN*TT*HID*4);
  float* h2     =(float*)alloc((size_t)NN*TT*HID*4);

  const int GN=(NN+255)/256, GE=(NE+255)/256;
  const int GMM=(NN+63)/64;              // 64 nodes/block
  const int GAGG=(NN*64+255)/256;        // 1 wave/node
  const int GGRU=(NN+63)/64;             // 64 nodes/block, 12 waves

  k_setup  <<<GN,256,0,stream>>>(cnt,Wih,Whh,W2);
  k_cnt    <<<GE,256,0,stream>>>(ei,cnt,pos);
  k_partA  <<<NB,256,0,stream>>>(cnt,bsum);
  k_midB   <<<1,256,0,stream>>>(bsum,bpre,offs);
  k_offsC  <<<NB,256,0,stream>>>(cnt,bpre,offs);
  k_scatter<<<GE,256,0,stream>>>(ei,ew,offs,pos,csr);
  k_deg    <<<GN,256,0,stream>>>(csr,offs,dis);
  k_normE  <<<GE,256,0,stream>>>(csr,dis);

  // layer 0
  k_mm0<<<GMM,256,0,stream>>>(x_seq, W0, A);
  k_agg<<<GAGG,256,0,stream>>>(A,b0,g0,be0,nullptr,h1,offs,csr,dis);
  // layer 1 (residual = h1)
  k_mm1<<<GMM,256,0,stream>>>(h1, W1, A);
  k_agg<<<GAGG,256,0,stream>>>(A,b1,g1,be1,h1,h2,offs,csr,dis);
  // fused GRU v5 (node-major LDS, pure-SMEM k-loops) + classifier
  k_gruF5<<<GGRU,768,0,stream>>>(h2, W2, bih,bhh, Wc1,bc1,Wc2,bc2, outp);
}

// Round 11
// 602.691 us; speedup vs baseline: 1.2064x; 1.0053x over previous
//
#include <hip/hip_runtime.h>
#include <hip/hip_fp16.h>
#include <math.h>

#define NN 50000
#define NE 800000
#define TT 6
#define HID 48
#define NB 196   // (NN+255)/256
#define XS 28    // node-major LDS row stride in u32 (112B, 16B-aligned, (7*lane+c)%8 quad-conflict-free)

__device__ __forceinline__ float sigmoidf_(float x){ return 1.0f/(1.0f+__expf(-x)); }
__device__ __forceinline__ float tanhf_(float x){
  float xc = fminf(fmaxf(x,-15.f),15.f);
  float t = __expf(2.f*xc);
  return (t-1.f)/(t+1.f);
}
__device__ __forceinline__ unsigned f2bf(float x){
  unsigned u = __float_as_uint(x);
  return (u + 0x7fffu + ((u>>16)&1u)) >> 16;   // RNE to bf16
}
__device__ __forceinline__ unsigned pack2(float a, float b){
  return f2bf(a) | (f2bf(b)<<16);
}
__device__ __forceinline__ float bflo(unsigned u){ return __uint_as_float(u<<16); }
__device__ __forceinline__ float bfhi(unsigned u){ return __uint_as_float(u & 0xffff0000u); }
__device__ __forceinline__ unsigned f2h(float x){
  return (unsigned)__half_as_ushort(__float2half(x));   // RNE fp16
}
__device__ __forceinline__ float h2f(unsigned u){
  return __half2float(__ushort_as_half((unsigned short)(u & 0xffffu)));
}
__device__ __forceinline__ unsigned pack2h(float a, float b){   // RNE fp16 pair
  return f2h(a) | (f2h(b)<<16);
}

typedef __fp16 h2t __attribute__((ext_vector_type(2)));

__device__ __forceinline__ unsigned pkrtz(float a, float b){    // fast packed cvt (RTZ)
#if __has_builtin(__builtin_amdgcn_cvt_pkrtz)
  auto r = __builtin_amdgcn_cvt_pkrtz(a, b);
  return __builtin_bit_cast(unsigned, r);
#else
  return pack2h(a, b);
#endif
}
// acc += lo(a)*lo(b) + hi(a)*hi(b), fp32 accumulate
__device__ __forceinline__ float dot2f(unsigned a, unsigned b, float c){
#if __has_builtin(__builtin_amdgcn_fdot2)
  return __builtin_amdgcn_fdot2(__builtin_bit_cast(h2t, a), __builtin_bit_cast(h2t, b), c, false);
#else
  h2t av = __builtin_bit_cast(h2t, a), bv = __builtin_bit_cast(h2t, b);
  return c + (float)av[0]*(float)bv[0] + (float)av[1]*(float)bv[1];
#endif
}

struct U3 { unsigned x,y,z; };

// 256-thread inclusive block scan (4 waves of 64)
__device__ __forceinline__ int block_scan_incl(int x, int* wsum){
  int lane = threadIdx.x & 63, w = threadIdx.x >> 6;
  int v = x;
#pragma unroll
  for(int d=1; d<64; d<<=1){
    int u = __shfl_up(v, d, 64);
    if(lane >= d) v += u;
  }
  if(lane==63) wsum[w] = v;
  __syncthreads();
  int add = 0;
#pragma unroll
  for(int k=0;k<3;k++) if(w>k) add += wsum[k];
  return v + add;
}

// ---------------- setup: cnt init + GRU weight repack (fp16 pairs along k) ----------------
// W2 [12 w][24 k2][24 c] u32: wave w owns hidden features 4w..4w+3.
//   c<12 : h-side (Whh), cc=c:   cc<4 -> r-row (4w+cc), cc<8 -> z-row (48+4w+cc-4), else n-row (96+4w+cc-8)
//   c>=12: x-side (Wih), cc=c-12, same row map.
__global__ __launch_bounds__(256) void k_setup(int* cnt,
                                               const float* __restrict__ Wih, const float* __restrict__ Whh,
                                               unsigned* W2){
  int i = blockIdx.x*256+threadIdx.x;
  if(i<NN) cnt[i]=0;
  if(i < 12*24*24){
    int w = i/576, r = i%576;
    int k2 = r/24, c = r%24;
    int cc = (c<12)? c : (c-12);
    int row = (cc<4) ? (w*4 + cc) : (cc<8) ? (48 + w*4 + cc-4) : (96 + w*4 + cc-8);
    const float* Wsrc = (c<12)? Whh : Wih;
    W2[i] = pack2h(Wsrc[row*48 + 2*k2], Wsrc[row*48 + 2*k2 + 1]);
  }
}

// single atomic per edge: rank within destination bucket
__global__ __launch_bounds__(256) void k_cnt(const int* __restrict__ ei, int* cnt, int* pos){
  int e = blockIdx.x*256+threadIdx.x;
  if(e<NE){
    int c = ei[NE+e];
    pos[e] = atomicAdd(&cnt[c], 1);
  }
}

// phase A: per-block sums of cnt
__global__ __launch_bounds__(256) void k_partA(const int* __restrict__ cnt, int* bsum){
  __shared__ int wsum[4];
  int i = blockIdx.x*256+threadIdx.x;
  int x = (i<NN)? cnt[i] : 0;
  int lane = threadIdx.x & 63, w = threadIdx.x >> 6;
  int v = x;
#pragma unroll
  for(int m=32;m>=1;m>>=1) v += __shfl_xor(v, m, 64);
  if(lane==0) wsum[w]=v;
  __syncthreads();
  if(threadIdx.x==0) bsum[blockIdx.x] = wsum[0]+wsum[1]+wsum[2]+wsum[3];
}

// phase B: exclusive scan of 196 block sums
__global__ __launch_bounds__(256) void k_midB(const int* __restrict__ bsum, int* bpre, int* offs){
  __shared__ int wsum[4];
  int t = threadIdx.x;
  int x = (t<NB)? bsum[t] : 0;
  int incl = block_scan_incl(x, wsum);
  if(t<NB) bpre[t] = incl - x;
  if(t==255) offs[NN] = incl;   // total
}

// phase C: per-block exclusive scan of cnt + bpre -> offs
__global__ __launch_bounds__(256) void k_offsC(const int* __restrict__ cnt, const int* __restrict__ bpre,
                                               int* offs){
  __shared__ int wsum[4];
  int i = blockIdx.x*256+threadIdx.x;
  int x = (i<NN)? cnt[i] : 0;
  int incl = block_scan_incl(x, wsum);
  if(i<NN) offs[i] = bpre[blockIdx.x] + incl - x;
}

// atomic-free scatter: csr[offs[c]+pos[e]] = (row, ew)
__global__ __launch_bounds__(256) void k_scatter(const int* __restrict__ ei, const float* __restrict__ ew,
                                                 const int* __restrict__ offs, const int* __restrict__ pos,
                                                 int2* __restrict__ csr){
  int e = blockIdx.x*256+threadIdx.x;
  if(e<NE){
    int c = ei[NE+e];
    int2 v; v.x = ei[e]; v.y = __float_as_int(ew[e]);
    csr[offs[c]+pos[e]] = v;
  }
}

// deg = 1 + row-sum of ew (atomic-free), dis = rsqrt(deg)  [deg>=1 always]
__global__ __launch_bounds__(256) void k_deg(const int2* __restrict__ csr, const int* __restrict__ offs,
                                             float* dis){
  int i = blockIdx.x*256+threadIdx.x;
  if(i<NN){
    float s = 1.f;
    int e0=offs[i], e1=offs[i+1];
    for(int j=e0;j<e1;j++) s += __int_as_float(csr[j].y);
    dis[i] = rsqrtf(s);
  }
}

// patch edge norm in place: y = dis[r]*ew   (dis[c] factored out in k_agg)
__global__ __launch_bounds__(256) void k_normE(int2* __restrict__ csr, const float* __restrict__ dis){
  int j = blockIdx.x*256+threadIdx.x;
  if(j<NE){
    int2 v = csr[j];
    v.y = __float_as_int(dis[v.x]*__int_as_float(v.y));
    csr[j] = v;
  }
}

// ---------------- layer-0 matmul: wave = feature slice (uniform), lane = node ----------------
// t-OUTER loop (r8 win): per-wave L1 window 4 KB vs 24 KB.
__global__ __launch_bounds__(256) void k_mm0(const float* __restrict__ X, const float* __restrict__ W,
                                             unsigned* __restrict__ A){
  int s = __builtin_amdgcn_readfirstlane(threadIdx.x>>6);   // 0..3, wave-uniform
  int n = blockIdx.x*64 + (threadIdx.x&63);
  if(n>=NN) return;
  const float* xb = X + (long long)n*64;
  const float* wb = W + 12*s;
  float acc[TT][12];
#pragma unroll
  for(int t=0;t<TT;t++)
#pragma unroll
    for(int j=0;j<12;j++) acc[t][j]=0.f;
#pragma unroll
  for(int t=0;t<TT;t++){                 // full unroll: acc[t] constant-indexed
    const float* xt = xb + (long long)t*NN*64;
#pragma unroll 2
    for(int k4=0;k4<16;k4++){
      float4 xv = *reinterpret_cast<const float4*>(xt + 4*k4);
#pragma unroll
      for(int q=0;q<4;q++){
        const float* wr = wb + (4*k4+q)*HID;
        float w[12];
#pragma unroll
        for(int j=0;j<12;j++) w[j]=wr[j];   // uniform addr -> s_load
        float xs = (&xv.x)[q];
#pragma unroll
        for(int j=0;j<12;j++) acc[t][j] = fmaf(xs, w[j], acc[t][j]);
      }
    }
  }
  unsigned buf[36];
#pragma unroll
  for(int j=0;j<12;j++){
    buf[3*j  ]=pack2(acc[0][j],acc[1][j]);
    buf[3*j+1]=pack2(acc[2][j],acc[3][j]);
    buf[3*j+2]=pack2(acc[4][j],acc[5][j]);
  }
  uint4* o4 = reinterpret_cast<uint4*>(A + (long long)n*144 + 36*s);
#pragma unroll
  for(int q=0;q<9;q++) o4[q] = make_uint4(buf[4*q],buf[4*q+1],buf[4*q+2],buf[4*q+3]);
}

// ---------------- layer-1 matmul (K=48), input fp32 [n][t][48], t-outer ----------------
__global__ __launch_bounds__(256) void k_mm1(const float* __restrict__ X, const float* __restrict__ W,
                                             unsigned* __restrict__ A){
  int s = __builtin_amdgcn_readfirstlane(threadIdx.x>>6);
  int n = blockIdx.x*64 + (threadIdx.x&63);
  if(n>=NN) return;
  const float* xb = X + (long long)n*(TT*HID);
  const float* wb = W + 12*s;
  float acc[TT][12];
#pragma unroll
  for(int t=0;t<TT;t++)
#pragma unroll
    for(int j=0;j<12;j++) acc[t][j]=0.f;
#pragma unroll
  for(int t=0;t<TT;t++){                 // full unroll: acc[t] constant-indexed
    const float* xt = xb + t*HID;
#pragma unroll 2
    for(int k4=0;k4<12;k4++){
      float4 xv = *reinterpret_cast<const float4*>(xt + 4*k4);
#pragma unroll
      for(int q=0;q<4;q++){
        const float* wr = wb + (4*k4+q)*HID;
        float w[12];
#pragma unroll
        for(int j=0;j<12;j++) w[j]=wr[j];
        float xs = (&xv.x)[q];
#pragma unroll
        for(int j=0;j<12;j++) acc[t][j] = fmaf(xs, w[j], acc[t][j]);
      }
    }
  }
  unsigned buf[36];
#pragma unroll
  for(int j=0;j<12;j++){
    buf[3*j  ]=pack2(acc[0][j],acc[1][j]);
    buf[3*j+1]=pack2(acc[2][j],acc[3][j]);
    buf[3*j+2]=pack2(acc[4][j],acc[5][j]);
  }
  uint4* o4 = reinterpret_cast<uint4*>(A + (long long)n*144 + 36*s);
#pragma unroll
  for(int q=0;q<9;q++) o4[q] = make_uint4(buf[4*q],buf[4*q+1],buf[4*q+2],buf[4*q+3]);
}

// ---------------- CSR aggregation (bf16 gather) + bias + LN + ReLU (+resid)
// SCALARIZED wave-uniform path (r11): wid forced scalar via readfirstlane ->
// offs/dis/csr reads become s_loads (batched, on lgkmcnt, overlapping the vmcnt
// A-gathers); edge loop is scalar-controlled; gather addr = SGPR base + constant
// per-lane offset. Per-edge VALU drops from ~15 to ~2. Arithmetic unchanged.
__global__ __launch_bounds__(256) void k_agg(const unsigned* __restrict__ A, const float* __restrict__ bias,
                                             const float* __restrict__ gain, const float* __restrict__ beta,
                                             const float* __restrict__ resid, float* __restrict__ out,
                                             const int* __restrict__ offs, const int2* __restrict__ csr,
                                             const float* __restrict__ dis){
  int wid = (int)((blockIdx.x*256+threadIdx.x)>>6);
  wid = __builtin_amdgcn_readfirstlane(wid);            // wave-uniform -> scalar
  int lane = threadIdx.x & 63;
  if(wid>=NN) return;
  const bool act = lane<HID;
  const int f = act? lane : (HID-1);
  const unsigned* Arow = A + 3*f;                       // SGPR base + per-lane const
  float dn = dis[wid];                                  // scalar load
  float acc[TT];
  {
    U3 v = *reinterpret_cast<const U3*>(Arow + (long long)wid*144);
    acc[0]=dn*bflo(v.x); acc[1]=dn*bfhi(v.x);
    acc[2]=dn*bflo(v.y); acc[3]=dn*bfhi(v.y);
    acc[4]=dn*bflo(v.z); acc[5]=dn*bfhi(v.z);
  }
  int e0=offs[wid], e1=offs[wid+1];                     // scalar loads
  int e=e0;
  for(; e+3<e1; e+=4){
    int2 i0=csr[e], i1=csr[e+1], i2=csr[e+2], i3=csr[e+3];   // scalar s_load_dwordx8
    U3 d0 = *reinterpret_cast<const U3*>(Arow + (long long)i0.x*144);
    U3 d1 = *reinterpret_cast<const U3*>(Arow + (long long)i1.x*144);
    U3 d2 = *reinterpret_cast<const U3*>(Arow + (long long)i2.x*144);
    U3 d3 = *reinterpret_cast<const U3*>(Arow + (long long)i3.x*144);
    float n0=__int_as_float(i0.y), n1=__int_as_float(i1.y);
    float n2=__int_as_float(i2.y), n3=__int_as_float(i3.y);
    acc[0]=fmaf(n0,bflo(d0.x),acc[0]); acc[1]=fmaf(n0,bfhi(d0.x),acc[1]);
    acc[2]=fmaf(n0,bflo(d0.y),acc[2]); acc[3]=fmaf(n0,bfhi(d0.y),acc[3]);
    acc[4]=fmaf(n0,bflo(d0.z),acc[4]); acc[5]=fmaf(n0,bfhi(d0.z),acc[5]);
    acc[0]=fmaf(n1,bflo(d1.x),acc[0]); acc[1]=fmaf(n1,bfhi(d1.x),acc[1]);
    acc[2]=fmaf(n1,bflo(d1.y),acc[2]); acc[3]=fmaf(n1,bfhi(d1.y),acc[3]);
    acc[4]=fmaf(n1,bflo(d1.z),acc[4]); acc[5]=fmaf(n1,bfhi(d1.z),acc[5]);
    acc[0]=fmaf(n2,bflo(d2.x),acc[0]); acc[1]=fmaf(n2,bfhi(d2.x),acc[1]);
    acc[2]=fmaf(n2,bflo(d2.y),acc[2]); acc[3]=fmaf(n2,bfhi(d2.y),acc[3]);
    acc[4]=fmaf(n2,bflo(d2.z),acc[4]); acc[5]=fmaf(n2,bfhi(d2.z),acc[5]);
    acc[0]=fmaf(n3,bflo(d3.x),acc[0]); acc[1]=fmaf(n3,bfhi(d3.x),acc[1]);
    acc[2]=fmaf(n3,bflo(d3.y),acc[2]); acc[3]=fmaf(n3,bfhi(d3.y),acc[3]);
    acc[4]=fmaf(n3,bflo(d3.z),acc[4]); acc[5]=fmaf(n3,bfhi(d3.z),acc[5]);
  }
  for(; e<e1; ++e){
    int2 i0=csr[e];
    U3 d0 = *reinterpret_cast<const U3*>(Arow + (long long)i0.x*144);
    float n0=__int_as_float(i0.y);
    acc[0]=fmaf(n0,bflo(d0.x),acc[0]); acc[1]=fmaf(n0,bfhi(d0.x),acc[1]);
    acc[2]=fmaf(n0,bflo(d0.y),acc[2]); acc[3]=fmaf(n0,bfhi(d0.y),acc[3]);
    acc[4]=fmaf(n0,bflo(d0.z),acc[4]); acc[5]=fmaf(n0,bfhi(d0.z),acc[5]);
  }
  float bb = bias[f], gg = gain[f], be = beta[f];
  const float rn = 1.0f/HID;
#pragma unroll
  for(int t=0;t<TT;t++){
    float val = fmaf(acc[t], dn, bb);    // final *dn fold
    float v = act? val : 0.f;
    float s = v, s2 = v*v;
#pragma unroll
    for(int m=32;m>=1;m>>=1){
      s  += __shfl_xor(s,  m, 64);
      s2 += __shfl_xor(s2, m, 64);
    }
    float mu  = s*rn;
    float var = fmaxf(s2*rn - mu*mu, 0.f);
    float y = (val-mu)*rsqrtf(var+1e-5f)*gg + be;
    y = fmaxf(y, 0.f);
    long long oidx = (long long)wid*(TT*HID) + t*HID + f;
    if(resid) y += resid[oidx];
    if(act) out[oidx] = y;
  }
}

// ---------------- fused GRU v5: node-major LDS rows + pure-SMEM k-loops ----------------
// block: 64 nodes, 768 threads = 12 waves. Wave w owns hidden features 4w..4w+3 (12 gate rows).
// x/h stored NODE-MAJOR: row = 28 u32 (112B, 16B-aligned). Per step each lane reads its
// whole row via 6 ds_read_b128 (quad-bank (7*lane+c)%8 -> conflict-free), then the k-loop
// is chunks of {4 named values x (ws[12] s_load + 12 dot2)} — no ds_read inside.
__global__ __launch_bounds__(768) void k_gruF5(const float* __restrict__ X,   // h2 [n][t][48]
                                               const unsigned* __restrict__ W2, // [12][24][24] u32
                                               const float* __restrict__ bih, const float* __restrict__ bhh,
                                               const float* __restrict__ Wc1, const float* __restrict__ bc1,
                                               const float* __restrict__ Wc2, const float* __restrict__ bc2,
                                               float* __restrict__ out){
  __shared__ __align__(16) unsigned xall[TT*64*XS];   // 42 KB
  __shared__ __align__(16) unsigned hb[2][64*XS];     // 14 KB
  int tid = threadIdx.x;
  int wv = __builtin_amdgcn_readfirstlane(tid>>6);   // 0..11, uniform
  int lane = tid & 63;
  int f0 = wv*4;
  long long n = (long long)blockIdx.x*64 + lane;

  // stage x: thread (nd,q) loads node nd's float4 chunk q for all 6 t; writes uint2 at
  // pair-bank (nd*14+q)%16 — ~2-way (free).
  {
    int nd = tid/12, q = tid-12*nd;
    long long g = (long long)blockIdx.x*64+nd; if(g>NN-1) g=NN-1;
    const float* xs = X + g*(TT*HID) + 4*q;
#pragma unroll
    for(int t=0;t<TT;t++){
      float4 v = *reinterpret_cast<const float4*>(xs + t*HID);
      *reinterpret_cast<uint2*>(&xall[t*64*XS + nd*XS + 2*q]) =
          make_uint2(pkrtz(v.x,v.y), pkrtz(v.z,v.w));
    }
  }
  for(int i=tid;i<64*XS;i+=768) hb[0][i]=0u;

  float rbi[4], zbi[4], nbi[4], rbh[4], zbh[4], nbh[4], hprev[4];
#pragma unroll
  for(int j=0;j<4;j++){
    rbi[j]=bih[f0+j]; zbi[j]=bih[48+f0+j]; nbi[j]=bih[96+f0+j];
    rbh[j]=bhh[f0+j]; zbh[j]=bhh[48+f0+j]; nbh[j]=bhh[96+f0+j];
    hprev[j]=0.f;
  }
  __syncthreads();   // xall + hb[0] ready

  int cur=0;
#pragma unroll
  for(int tp=0; tp<2; tp++){
    // ---- phase 1: gi for steps 3tp..3tp+2 (x-side only, barrier-free) ----
    unsigned gi[18];
#pragma unroll
    for(int s=0;s<3;s++){
      float a[12];
#pragma unroll
      for(int j=0;j<4;j++){ a[j]=rbi[j]; a[4+j]=zbi[j]; a[8+j]=nbi[j]; }
      const uint4* xrow = reinterpret_cast<const uint4*>(&xall[(tp*3+s)*64*XS + lane*XS]);
      const unsigned* wbx = W2 + wv*24*24 + 12;   // x-slice base
#pragma unroll 2
      for(int c6=0;c6<6;c6++){
        uint4 hq = xrow[c6];                      // ds_read_b128, conflict-free
        unsigned xv_[4] = {hq.x, hq.y, hq.z, hq.w};
#pragma unroll
        for(int j4=0;j4<4;j4++){
          const unsigned* wp = wbx + (4*c6+j4)*24;
          unsigned ws[12];
#pragma unroll
          for(int q=0;q<12;q++) ws[q]=wp[q];      // uniform -> s_load
#pragma unroll
          for(int c=0;c<12;c++) a[c]=dot2f(xv_[j4], ws[c], a[c]);
        }
      }
#pragma unroll
      for(int m=0;m<6;m++) gi[s*6+m]=pack2h(a[2*m], a[2*m+1]);
    }
    // ---- phase 2: 3 recurrence steps (h-weights sK$-resident, pure-SMEM k-loop) ----
#pragma unroll
    for(int s=0;s<3;s++){
      float acc[12];
#pragma unroll
      for(int j=0;j<4;j++){ acc[j]=rbh[j]; acc[4+j]=zbh[j]; acc[8+j]=nbh[j]; }
      const uint4* hrow = reinterpret_cast<const uint4*>(&hb[cur][lane*XS]);
      const unsigned* wbh = W2 + wv*24*24;        // h-slice base
#pragma unroll 2
      for(int c6=0;c6<6;c6++){
        uint4 hq = hrow[c6];                      // ds_read_b128, conflict-free
        unsigned hv_[4] = {hq.x, hq.y, hq.z, hq.w};
#pragma unroll
        for(int j4=0;j4<4;j4++){
          const unsigned* wp = wbh + (4*c6+j4)*24;
          unsigned ws[12];
#pragma unroll
          for(int q=0;q<12;q++) ws[q]=wp[q];      // uniform -> s_load
#pragma unroll
          for(int c=0;c<12;c++) acc[c]=dot2f(hv_[j4], ws[c], acc[c]);
        }
      }
      float hn[4];
#pragma unroll
      for(int j=0;j<4;j++){
        unsigned pr=gi[s*6+(j>>1)], pz=gi[s*6+2+(j>>1)], pn=gi[s*6+4+(j>>1)];
        float gir=(j&1)? h2f(pr>>16):h2f(pr);
        float giz=(j&1)? h2f(pz>>16):h2f(pz);
        float gin=(j&1)? h2f(pn>>16):h2f(pn);
        float r  = sigmoidf_(acc[j]+gir);
        float zg = sigmoidf_(acc[4+j]+giz);
        float ng = tanhf_(gin + r*acc[8+j]);
        float hv = (1.f-zg)*ng + zg*hprev[j];
        hprev[j]=hv; hn[j]=hv;
      }
      *reinterpret_cast<uint2*>(&hb[cur^1][lane*XS + 2*wv]) =
          make_uint2(pack2h(hn[0],hn[1]), pack2h(hn[2],hn[3]));
      __syncthreads();   // next buffer fully written
      cur^=1;
    }
  }

  // classifier epilogue: wave 0 covers the block's 64 nodes
  if(wv==0 && n<NN){
    unsigned hh[24];
    {
      const uint4* hrow = reinterpret_cast<const uint4*>(&hb[cur][lane*XS]);
#pragma unroll
      for(int c6=0;c6<6;c6++){
        uint4 v = hrow[c6];
        hh[4*c6]=v.x; hh[4*c6+1]=v.y; hh[4*c6+2]=v.z; hh[4*c6+3]=v.w;
      }
    }
    float hv[24];
#pragma unroll
    for(int j=0;j<24;j++) hv[j]=bc1[j];
#pragma unroll 2
    for(int k2=0;k2<24;k2++){
      float hk0 = h2f(hh[k2]), hk1 = h2f(hh[k2]>>16);
      const float* w0 = Wc1 + (2*k2)*24;     // uniform -> s_load
      const float* w1 = Wc1 + (2*k2+1)*24;
#pragma unroll
      for(int j=0;j<24;j++) hv[j] = fmaf(hk0, w0[j], hv[j]);
#pragma unroll
      for(int j=0;j<24;j++) hv[j] = fmaf(hk1, w1[j], hv[j]);
    }
    float l0=bc2[0], l1=bc2[1];
#pragma unroll
    for(int j=0;j<24;j++){
      float a = fmaxf(hv[j],0.f);
      l0 = fmaf(a, Wc2[2*j],   l0);
      l1 = fmaf(a, Wc2[2*j+1], l1);
    }
    reinterpret_cast<float2*>(out)[n] = make_float2(l0,l1);
  }
}

static inline size_t al256(size_t x){ return (x+255)&~(size_t)255; }

extern "C" void kernel_launch(void* const* d_in, const int* in_sizes, int n_in,
                              void* d_out, int out_size, void* d_ws, size_t ws_size,
                              hipStream_t stream){
  const float* x_seq=(const float*)d_in[0];
  const int*   ei   =(const int*)d_in[1];
  const float* ew   =(const float*)d_in[2];
  const float* W0=(const float*)d_in[3];  const float* b0=(const float*)d_in[4];
  const float* g0=(const float*)d_in[5];  const float* be0=(const float*)d_in[6];
  const float* W1=(const float*)d_in[7];  const float* b1=(const float*)d_in[8];
  const float* g1=(const float*)d_in[9];  const float* be1=(const float*)d_in[10];
  const float* Wih=(const float*)d_in[11];const float* Whh=(const float*)d_in[12];
  const float* bih=(const float*)d_in[13];const float* bhh=(const float*)d_in[14];
  const float* Wc1=(const float*)d_in[15];const float* bc1=(const float*)d_in[16];
  const float* Wc2=(const float*)d_in[17];const float* bc2=(const float*)d_in[18];
  float* outp=(float*)d_out;

  char* p=(char*)d_ws; size_t off=0;
  auto alloc=[&](size_t bytes)->void*{ void* r=p+off; off=al256(off+bytes); return r; };
  float* dis    =(float*)alloc((size_t)NN*4);
  int*   cnt    =(int*)  alloc((size_t)NN*4);
  int*   offs   =(int*)  alloc((size_t)(NN+1)*4);
  int*   bsum   =(int*)  alloc((size_t)NB*4);
  int*   bpre   =(int*)  alloc((size_t)NB*4);
  int*   pos    =(int*)  alloc((size_t)NE*4);
  int2*  csr    =(int2*) alloc((size_t)NE*8);
  unsigned* W2  =(unsigned*)alloc((size_t)12*24*24*4);
  unsigned* A   =(unsigned*)alloc((size_t)NN*576 + 1024);   // bf16 [n][f][t6], 576B/row
  float* h1     =(float*)alloc((size_t)NN*TT*HID*4);
  float* h2     =(float*)alloc((size_t)NN*TT*HID*4);

  const int GN=(NN+255)/256, GE=(NE+255)/256;
  const int GMM=(NN+63)/64;              // 64 nodes/block
  const int GAGG=(NN*64+255)/256;        // 1 wave/node
  const int GGRU=(NN+63)/64;             // 64 nodes/block, 12 waves

  k_setup  <<<GN,256,0,stream>>>(cnt,Wih,Whh,W2);
  k_cnt    <<<GE,256,0,stream>>>(ei,cnt,pos);
  k_partA  <<<NB,256,0,stream>>>(cnt,bsum);
  k_midB   <<<1,256,0,stream>>>(bsum,bpre,offs);
  k_offsC  <<<NB,256,0,stream>>>(cnt,bpre,offs);
  k_scatter<<<GE,256,0,stream>>>(ei,ew,offs,pos,csr);
  k_deg    <<<GN,256,0,stream>>>(csr,offs,dis);
  k_normE  <<<GE,256,0,stream>>>(csr,dis);

  // layer 0
  k_mm0<<<GMM,256,0,stream>>>(x_seq, W0, A);
  k_agg<<<GAGG,256,0,stream>>>(A,b0,g0,be0,nullptr,h1,offs,csr,dis);
  // layer 1 (residual = h1)
  k_mm1<<<GMM,256,0,stream>>>(h1, W1, A);
  k_agg<<<GAGG,256,0,stream>>>(A,b1,g1,be1,h1,h2,offs,csr,dis);
  // fused GRU v5 (node-major LDS, pure-SMEM k-loops) + classifier
  k_gruF5<<<GGRU,768,0,stream>>>(h2, W2, bih,bhh, Wc1,bc1,Wc2,bc2, outp);
}

// Round 12
// 598.783 us; speedup vs baseline: 1.2142x; 1.0065x over previous
//
#include <hip/hip_runtime.h>
#include <hip/hip_fp16.h>
#include <math.h>

#define NN 50000
#define NE 800000
#define TT 6
#define HID 48
#define NB 196   // (NN+255)/256
#define XS 28    // node-major LDS row stride in u32 (112B, 16B-aligned, (7*lane+c)%8 quad-conflict-free)
#define AW 160   // A row stride in u32: 640B = 5 x 128B cachelines, every row line-aligned

__device__ __forceinline__ float sigmoidf_(float x){ return 1.0f/(1.0f+__expf(-x)); }
__device__ __forceinline__ float tanhf_(float x){
  float xc = fminf(fmaxf(x,-15.f),15.f);
  float t = __expf(2.f*xc);
  return (t-1.f)/(t+1.f);
}
__device__ __forceinline__ unsigned f2bf(float x){
  unsigned u = __float_as_uint(x);
  return (u + 0x7fffu + ((u>>16)&1u)) >> 16;   // RNE to bf16
}
__device__ __forceinline__ unsigned pack2(float a, float b){
  return f2bf(a) | (f2bf(b)<<16);
}
__device__ __forceinline__ float bflo(unsigned u){ return __uint_as_float(u<<16); }
__device__ __forceinline__ float bfhi(unsigned u){ return __uint_as_float(u & 0xffff0000u); }
__device__ __forceinline__ unsigned f2h(float x){
  return (unsigned)__half_as_ushort(__float2half(x));   // RNE fp16
}
__device__ __forceinline__ float h2f(unsigned u){
  return __half2float(__ushort_as_half((unsigned short)(u & 0xffffu)));
}
__device__ __forceinline__ unsigned pack2h(float a, float b){   // RNE fp16 pair
  return f2h(a) | (f2h(b)<<16);
}

typedef __fp16 h2t __attribute__((ext_vector_type(2)));

// acc += lo(a)*lo(b) + hi(a)*hi(b), fp32 accumulate
__device__ __forceinline__ float dot2f(unsigned a, unsigned b, float c){
#if __has_builtin(__builtin_amdgcn_fdot2)
  return __builtin_amdgcn_fdot2(__builtin_bit_cast(h2t, a), __builtin_bit_cast(h2t, b), c, false);
#else
  h2t av = __builtin_bit_cast(h2t, a), bv = __builtin_bit_cast(h2t, b);
  return c + (float)av[0]*(float)bv[0] + (float)av[1]*(float)bv[1];
#endif
}

struct U3 { unsigned x,y,z; };

// 256-thread inclusive block scan (4 waves of 64)
__device__ __forceinline__ int block_scan_incl(int x, int* wsum){
  int lane = threadIdx.x & 63, w = threadIdx.x >> 6;
  int v = x;
#pragma unroll
  for(int d=1; d<64; d<<=1){
    int u = __shfl_up(v, d, 64);
    if(lane >= d) v += u;
  }
  if(lane==63) wsum[w] = v;
  __syncthreads();
  int add = 0;
#pragma unroll
  for(int k=0;k<3;k++) if(w>k) add += wsum[k];
  return v + add;
}

// ---------------- setup: cnt init + GRU weight repack (fp16 pairs along k) ----------------
// W2 [12 w][24 k2][24 c] u32: wave w owns hidden features 4w..4w+3.
//   c<12 : h-side (Whh), cc=c:   cc<4 -> r-row (4w+cc), cc<8 -> z-row (48+4w+cc-4), else n-row (96+4w+cc-8)
//   c>=12: x-side (Wih), cc=c-12, same row map.
__global__ __launch_bounds__(256) void k_setup(int* cnt,
                                               const float* __restrict__ Wih, const float* __restrict__ Whh,
                                               unsigned* W2){
  int i = blockIdx.x*256+threadIdx.x;
  if(i<NN) cnt[i]=0;
  if(i < 12*24*24){
    int w = i/576, r = i%576;
    int k2 = r/24, c = r%24;
    int cc = (c<12)? c : (c-12);
    int row = (cc<4) ? (w*4 + cc) : (cc<8) ? (48 + w*4 + cc-4) : (96 + w*4 + cc-8);
    const float* Wsrc = (c<12)? Whh : Wih;
    W2[i] = pack2h(Wsrc[row*48 + 2*k2], Wsrc[row*48 + 2*k2 + 1]);
  }
}

// single atomic per edge: rank within destination bucket
__global__ __launch_bounds__(256) void k_cnt(const int* __restrict__ ei, int* cnt, int* pos){
  int e = blockIdx.x*256+threadIdx.x;
  if(e<NE){
    int c = ei[NE+e];
    pos[e] = atomicAdd(&cnt[c], 1);
  }
}

// phase A: per-block sums of cnt
__global__ __launch_bounds__(256) void k_partA(const int* __restrict__ cnt, int* bsum){
  __shared__ int wsum[4];
  int i = blockIdx.x*256+threadIdx.x;
  int x = (i<NN)? cnt[i] : 0;
  int lane = threadIdx.x & 63, w = threadIdx.x >> 6;
  int v = x;
#pragma unroll
  for(int m=32;m>=1;m>>=1) v += __shfl_xor(v, m, 64);
  if(lane==0) wsum[w]=v;
  __syncthreads();
  if(threadIdx.x==0) bsum[blockIdx.x] = wsum[0]+wsum[1]+wsum[2]+wsum[3];
}

// phase B: exclusive scan of 196 block sums
__global__ __launch_bounds__(256) void k_midB(const int* __restrict__ bsum, int* bpre, int* offs){
  __shared__ int wsum[4];
  int t = threadIdx.x;
  int x = (t<NB)? bsum[t] : 0;
  int incl = block_scan_incl(x, wsum);
  if(t<NB) bpre[t] = incl - x;
  if(t==255) offs[NN] = incl;   // total
}

// phase C: per-block exclusive scan of cnt + bpre -> offs
__global__ __launch_bounds__(256) void k_offsC(const int* __restrict__ cnt, const int* __restrict__ bpre,
                                               int* offs){
  __shared__ int wsum[4];
  int i = blockIdx.x*256+threadIdx.x;
  int x = (i<NN)? cnt[i] : 0;
  int incl = block_scan_incl(x, wsum);
  if(i<NN) offs[i] = bpre[blockIdx.x] + incl - x;
}

// atomic-free scatter: csr[offs[c]+pos[e]] = (row, ew)
__global__ __launch_bounds__(256) void k_scatter(const int* __restrict__ ei, const float* __restrict__ ew,
                                                 const int* __restrict__ offs, const int* __restrict__ pos,
                                                 int2* __restrict__ csr){
  int e = blockIdx.x*256+threadIdx.x;
  if(e<NE){
    int c = ei[NE+e];
    int2 v; v.x = ei[e]; v.y = __float_as_int(ew[e]);
    csr[offs[c]+pos[e]] = v;
  }
}

// deg = 1 + row-sum of ew (atomic-free), dis = rsqrt(deg)  [deg>=1 always]
__global__ __launch_bounds__(256) void k_deg(const int2* __restrict__ csr, const int* __restrict__ offs,
                                             float* dis){
  int i = blockIdx.x*256+threadIdx.x;
  if(i<NN){
    float s = 1.f;
    int e0=offs[i], e1=offs[i+1];
    for(int j=e0;j<e1;j++) s += __int_as_float(csr[j].y);
    dis[i] = rsqrtf(s);
  }
}

// patch edge norm in place: y = dis[r]*ew   (dis[c] factored out in k_agg)
__global__ __launch_bounds__(256) void k_normE(int2* __restrict__ csr, const float* __restrict__ dis){
  int j = blockIdx.x*256+threadIdx.x;
  if(j<NE){
    int2 v = csr[j];
    v.y = __float_as_int(dis[v.x]*__int_as_float(v.y));
    csr[j] = v;
  }
}

// ---------------- layer-0 matmul: wave = feature slice (uniform), lane = node ----------------
// t-OUTER loop (r8 win): per-wave L1 window 4 KB vs 24 KB.
// A row per node = AW=160 words (640B, line-aligned); data in words 0..143.
__global__ __launch_bounds__(256) void k_mm0(const float* __restrict__ X, const float* __restrict__ W,
                                             unsigned* __restrict__ A){
  int s = __builtin_amdgcn_readfirstlane(threadIdx.x>>6);   // 0..3, wave-uniform
  int n = blockIdx.x*64 + (threadIdx.x&63);
  if(n>=NN) return;
  const float* xb = X + (long long)n*64;
  const float* wb = W + 12*s;
  float acc[TT][12];
#pragma unroll
  for(int t=0;t<TT;t++)
#pragma unroll
    for(int j=0;j<12;j++) acc[t][j]=0.f;
#pragma unroll
  for(int t=0;t<TT;t++){                 // full unroll: acc[t] constant-indexed
    const float* xt = xb + (long long)t*NN*64;
#pragma unroll 2
    for(int k4=0;k4<16;k4++){
      float4 xv = *reinterpret_cast<const float4*>(xt + 4*k4);
#pragma unroll
      for(int q=0;q<4;q++){
        const float* wr = wb + (4*k4+q)*HID;
        float w[12];
#pragma unroll
        for(int j=0;j<12;j++) w[j]=wr[j];   // uniform addr -> s_load
        float xs = (&xv.x)[q];
#pragma unroll
        for(int j=0;j<12;j++) acc[t][j] = fmaf(xs, w[j], acc[t][j]);
      }
    }
  }
  unsigned buf[36];
#pragma unroll
  for(int j=0;j<12;j++){
    buf[3*j  ]=pack2(acc[0][j],acc[1][j]);
    buf[3*j+1]=pack2(acc[2][j],acc[3][j]);
    buf[3*j+2]=pack2(acc[4][j],acc[5][j]);
  }
  uint4* o4 = reinterpret_cast<uint4*>(A + (long long)n*AW + 36*s);
#pragma unroll
  for(int q=0;q<9;q++) o4[q] = make_uint4(buf[4*q],buf[4*q+1],buf[4*q+2],buf[4*q+3]);
}

// ---------------- layer-1 matmul (K=48), input fp32 [n][t][48], t-outer ----------------
__global__ __launch_bounds__(256) void k_mm1(const float* __restrict__ X, const float* __restrict__ W,
                                             unsigned* __restrict__ A){
  int s = __builtin_amdgcn_readfirstlane(threadIdx.x>>6);
  int n = blockIdx.x*64 + (threadIdx.x&63);
  if(n>=NN) return;
  const float* xb = X + (long long)n*(TT*HID);
  const float* wb = W + 12*s;
  float acc[TT][12];
#pragma unroll
  for(int t=0;t<TT;t++)
#pragma unroll
    for(int j=0;j<12;j++) acc[t][j]=0.f;
#pragma unroll
  for(int t=0;t<TT;t++){                 // full unroll: acc[t] constant-indexed
    const float* xt = xb + t*HID;
#pragma unroll 2
    for(int k4=0;k4<12;k4++){
      float4 xv = *reinterpret_cast<const float4*>(xt + 4*k4);
#pragma unroll
      for(int q=0;q<4;q++){
        const float* wr = wb + (4*k4+q)*HID;
        float w[12];
#pragma unroll
        for(int j=0;j<12;j++) w[j]=wr[j];
        float xs = (&xv.x)[q];
#pragma unroll
        for(int j=0;j<12;j++) acc[t][j] = fmaf(xs, w[j], acc[t][j]);
      }
    }
  }
  unsigned buf[36];
#pragma unroll
  for(int j=0;j<12;j++){
    buf[3*j  ]=pack2(acc[0][j],acc[1][j]);
    buf[3*j+1]=pack2(acc[2][j],acc[3][j]);
    buf[3*j+2]=pack2(acc[4][j],acc[5][j]);
  }
  uint4* o4 = reinterpret_cast<uint4*>(A + (long long)n*AW + 36*s);
#pragma unroll
  for(int q=0;q<9;q++) o4[q] = make_uint4(buf[4*q],buf[4*q+1],buf[4*q+2],buf[4*q+3]);
}

// ---------------- CSR aggregation (bf16 gather) + bias + LN + ReLU (+resid)
// Scalarized wave-uniform path (r11). A rows 640B line-aligned (r12): every edge gather
// is exactly 5 cachelines (was avg 5.5 unaligned).
// out   : optional fp32 [n][t][48] output (layer 0 -> h1, needed for resid+mm1)
// out_pk: optional packed-fp16 [n][t][24 u32] output (layer 1 -> h2p, feeds GRU directly)
__global__ __launch_bounds__(256) void k_agg(const unsigned* __restrict__ A, const float* __restrict__ bias,
                                             const float* __restrict__ gain, const float* __restrict__ beta,
                                             const float* __restrict__ resid, float* __restrict__ out,
                                             unsigned* __restrict__ out_pk,
                                             const int* __restrict__ offs, const int2* __restrict__ csr,
                                             const float* __restrict__ dis){
  int wid = (int)((blockIdx.x*256+threadIdx.x)>>6);
  wid = __builtin_amdgcn_readfirstlane(wid);            // wave-uniform -> scalar
  int lane = threadIdx.x & 63;
  if(wid>=NN) return;
  const bool act = lane<HID;
  const int f = act? lane : (HID-1);
  const unsigned* Arow = A + 3*f;                       // SGPR base + per-lane const
  float dn = dis[wid];                                  // scalar load
  float acc[TT];
  {
    U3 v = *reinterpret_cast<const U3*>(Arow + (long long)wid*AW);
    acc[0]=dn*bflo(v.x); acc[1]=dn*bfhi(v.x);
    acc[2]=dn*bflo(v.y); acc[3]=dn*bfhi(v.y);
    acc[4]=dn*bflo(v.z); acc[5]=dn*bfhi(v.z);
  }
  int e0=offs[wid], e1=offs[wid+1];                     // scalar loads
  int e=e0;
  for(; e+3<e1; e+=4){
    int2 i0=csr[e], i1=csr[e+1], i2=csr[e+2], i3=csr[e+3];   // scalar s_loads
    U3 d0 = *reinterpret_cast<const U3*>(Arow + (long long)i0.x*AW);
    U3 d1 = *reinterpret_cast<const U3*>(Arow + (long long)i1.x*AW);
    U3 d2 = *reinterpret_cast<const U3*>(Arow + (long long)i2.x*AW);
    U3 d3 = *reinterpret_cast<const U3*>(Arow + (long long)i3.x*AW);
    float n0=__int_as_float(i0.y), n1=__int_as_float(i1.y);
    float n2=__int_as_float(i2.y), n3=__int_as_float(i3.y);
    acc[0]=fmaf(n0,bflo(d0.x),acc[0]); acc[1]=fmaf(n0,bfhi(d0.x),acc[1]);
    acc[2]=fmaf(n0,bflo(d0.y),acc[2]); acc[3]=fmaf(n0,bfhi(d0.y),acc[3]);
    acc[4]=fmaf(n0,bflo(d0.z),acc[4]); acc[5]=fmaf(n0,bfhi(d0.z),acc[5]);
    acc[0]=fmaf(n1,bflo(d1.x),acc[0]); acc[1]=fmaf(n1,bfhi(d1.x),acc[1]);
    acc[2]=fmaf(n1,bflo(d1.y),acc[2]); acc[3]=fmaf(n1,bfhi(d1.y),acc[3]);
    acc[4]=fmaf(n1,bflo(d1.z),acc[4]); acc[5]=fmaf(n1,bfhi(d1.z),acc[5]);
    acc[0]=fmaf(n2,bflo(d2.x),acc[0]); acc[1]=fmaf(n2,bfhi(d2.x),acc[1]);
    acc[2]=fmaf(n2,bflo(d2.y),acc[2]); acc[3]=fmaf(n2,bfhi(d2.y),acc[3]);
    acc[4]=fmaf(n2,bflo(d2.z),acc[4]); acc[5]=fmaf(n2,bfhi(d2.z),acc[5]);
    acc[0]=fmaf(n3,bflo(d3.x),acc[0]); acc[1]=fmaf(n3,bfhi(d3.x),acc[1]);
    acc[2]=fmaf(n3,bflo(d3.y),acc[2]); acc[3]=fmaf(n3,bfhi(d3.y),acc[3]);
    acc[4]=fmaf(n3,bflo(d3.z),acc[4]); acc[5]=fmaf(n3,bfhi(d3.z),acc[5]);
  }
  for(; e<e1; ++e){
    int2 i0=csr[e];
    U3 d0 = *reinterpret_cast<const U3*>(Arow + (long long)i0.x*AW);
    float n0=__int_as_float(i0.y);
    acc[0]=fmaf(n0,bflo(d0.x),acc[0]); acc[1]=fmaf(n0,bfhi(d0.x),acc[1]);
    acc[2]=fmaf(n0,bflo(d0.y),acc[2]); acc[3]=fmaf(n0,bfhi(d0.y),acc[3]);
    acc[4]=fmaf(n0,bflo(d0.z),acc[4]); acc[5]=fmaf(n0,bfhi(d0.z),acc[5]);
  }
  float bb = bias[f], gg = gain[f], be = beta[f];
  const float rn = 1.0f/HID;
#pragma unroll
  for(int t=0;t<TT;t++){
    float val = fmaf(acc[t], dn, bb);    // final *dn fold
    float v = act? val : 0.f;
    float s = v, s2 = v*v;
#pragma unroll
    for(int m=32;m>=1;m>>=1){
      s  += __shfl_xor(s,  m, 64);
      s2 += __shfl_xor(s2, m, 64);
    }
    float mu  = s*rn;
    float var = fmaxf(s2*rn - mu*mu, 0.f);
    float y = (val-mu)*rsqrtf(var+1e-5f)*gg + be;
    y = fmaxf(y, 0.f);
    long long oidx = (long long)wid*(TT*HID) + t*HID + f;
    if(resid) y += resid[oidx];
    if(out){
      if(act) out[oidx] = y;
    }
    if(out_pk){
      float yn = __shfl_xor(y, 1, 64);   // pair feature f^1
      if(act && !(lane&1))
        out_pk[(long long)wid*144 + t*24 + (lane>>1)] = pack2h(y, yn);
    }
  }
}

// ---------------- fused GRU v5: node-major LDS rows + pure-SMEM k-loops ----------------
// block: 64 nodes, 768 threads = 12 waves. Wave w owns hidden features 4w..4w+3 (12 gate rows).
// x input now PRE-PACKED fp16 pairs [n][t][24 u32] (written by layer-1 k_agg) — stage is a
// pure uint2 copy (no pkrtz), half the global read bytes of the fp32 path.
__global__ __launch_bounds__(768) void k_gruF5(const unsigned* __restrict__ Xp,  // h2 packed [n][144] u32
                                               const unsigned* __restrict__ W2, // [12][24][24] u32
                                               const float* __restrict__ bih, const float* __restrict__ bhh,
                                               const float* __restrict__ Wc1, const float* __restrict__ bc1,
                                               const float* __restrict__ Wc2, const float* __restrict__ bc2,
                                               float* __restrict__ out){
  __shared__ __align__(16) unsigned xall[TT*64*XS];   // 42 KB
  __shared__ __align__(16) unsigned hb[2][64*XS];     // 14 KB
  int tid = threadIdx.x;
  int wv = __builtin_amdgcn_readfirstlane(tid>>6);   // 0..11, uniform
  int lane = tid & 63;
  int f0 = wv*4;
  long long n = (long long)blockIdx.x*64 + lane;

  // stage x: thread (nd,q) copies node nd's uint2 chunk q for all 6 t; LDS write at
  // pair-bank (nd*14+q)%16 — ~2-way (free).
  {
    int nd = tid/12, q = tid-12*nd;
    long long g = (long long)blockIdx.x*64+nd; if(g>NN-1) g=NN-1;
    const unsigned* xs = Xp + g*144 + 2*q;
#pragma unroll
    for(int t=0;t<TT;t++){
      uint2 v = *reinterpret_cast<const uint2*>(xs + t*24);
      *reinterpret_cast<uint2*>(&xall[t*64*XS + nd*XS + 2*q]) = v;
    }
  }
  for(int i=tid;i<64*XS;i+=768) hb[0][i]=0u;

  float rbi[4], zbi[4], nbi[4], rbh[4], zbh[4], nbh[4], hprev[4];
#pragma unroll
  for(int j=0;j<4;j++){
    rbi[j]=bih[f0+j]; zbi[j]=bih[48+f0+j]; nbi[j]=bih[96+f0+j];
    rbh[j]=bhh[f0+j]; zbh[j]=bhh[48+f0+j]; nbh[j]=bhh[96+f0+j];
    hprev[j]=0.f;
  }
  __syncthreads();   // xall + hb[0] ready

  int cur=0;
#pragma unroll
  for(int tp=0; tp<2; tp++){
    // ---- phase 1: gi for steps 3tp..3tp+2 (x-side only, barrier-free) ----
    unsigned gi[18];
#pragma unroll
    for(int s=0;s<3;s++){
      float a[12];
#pragma unroll
      for(int j=0;j<4;j++){ a[j]=rbi[j]; a[4+j]=zbi[j]; a[8+j]=nbi[j]; }
      const uint4* xrow = reinterpret_cast<const uint4*>(&xall[(tp*3+s)*64*XS + lane*XS]);
      const unsigned* wbx = W2 + wv*24*24 + 12;   // x-slice base
#pragma unroll 2
      for(int c6=0;c6<6;c6++){
        uint4 hq = xrow[c6];                      // ds_read_b128, conflict-free
        unsigned xv_[4] = {hq.x, hq.y, hq.z, hq.w};
#pragma unroll
        for(int j4=0;j4<4;j4++){
          const unsigned* wp = wbx + (4*c6+j4)*24;
          unsigned ws[12];
#pragma unroll
          for(int q=0;q<12;q++) ws[q]=wp[q];      // uniform -> s_load
#pragma unroll
          for(int c=0;c<12;c++) a[c]=dot2f(xv_[j4], ws[c], a[c]);
        }
      }
#pragma unroll
      for(int m=0;m<6;m++) gi[s*6+m]=pack2h(a[2*m], a[2*m+1]);
    }
    // ---- phase 2: 3 recurrence steps (h-weights sK$-resident, pure-SMEM k-loop) ----
#pragma unroll
    for(int s=0;s<3;s++){
      float acc[12];
#pragma unroll
      for(int j=0;j<4;j++){ acc[j]=rbh[j]; acc[4+j]=zbh[j]; acc[8+j]=nbh[j]; }
      const uint4* hrow = reinterpret_cast<const uint4*>(&hb[cur][lane*XS]);
      const unsigned* wbh = W2 + wv*24*24;        // h-slice base
#pragma unroll 2
      for(int c6=0;c6<6;c6++){
        uint4 hq = hrow[c6];                      // ds_read_b128, conflict-free
        unsigned hv_[4] = {hq.x, hq.y, hq.z, hq.w};
#pragma unroll
        for(int j4=0;j4<4;j4++){
          const unsigned* wp = wbh + (4*c6+j4)*24;
          unsigned ws[12];
#pragma unroll
          for(int q=0;q<12;q++) ws[q]=wp[q];      // uniform -> s_load
#pragma unroll
          for(int c=0;c<12;c++) acc[c]=dot2f(hv_[j4], ws[c], acc[c]);
        }
      }
      float hn[4];
#pragma unroll
      for(int j=0;j<4;j++){
        unsigned pr=gi[s*6+(j>>1)], pz=gi[s*6+2+(j>>1)], pn=gi[s*6+4+(j>>1)];
        float gir=(j&1)? h2f(pr>>16):h2f(pr);
        float giz=(j&1)? h2f(pz>>16):h2f(pz);
        float gin=(j&1)? h2f(pn>>16):h2f(pn);
        float r  = sigmoidf_(acc[j]+gir);
        float zg = sigmoidf_(acc[4+j]+giz);
        float ng = tanhf_(gin + r*acc[8+j]);
        float hv = (1.f-zg)*ng + zg*hprev[j];
        hprev[j]=hv; hn[j]=hv;
      }
      *reinterpret_cast<uint2*>(&hb[cur^1][lane*XS + 2*wv]) =
          make_uint2(pack2h(hn[0],hn[1]), pack2h(hn[2],hn[3]));
      __syncthreads();   // next buffer fully written
      cur^=1;
    }
  }

  // classifier epilogue: wave 0 covers the block's 64 nodes
  if(wv==0 && n<NN){
    unsigned hh[24];
    {
      const uint4* hrow = reinterpret_cast<const uint4*>(&hb[cur][lane*XS]);
#pragma unroll
      for(int c6=0;c6<6;c6++){
        uint4 v = hrow[c6];
        hh[4*c6]=v.x; hh[4*c6+1]=v.y; hh[4*c6+2]=v.z; hh[4*c6+3]=v.w;
      }
    }
    float hv[24];
#pragma unroll
    for(int j=0;j<24;j++) hv[j]=bc1[j];
#pragma unroll 2
    for(int k2=0;k2<24;k2++){
      float hk0 = h2f(hh[k2]), hk1 = h2f(hh[k2]>>16);
      const float* w0 = Wc1 + (2*k2)*24;     // uniform -> s_load
      const float* w1 = Wc1 + (2*k2+1)*24;
#pragma unroll
      for(int j=0;j<24;j++) hv[j] = fmaf(hk0, w0[j], hv[j]);
#pragma unroll
      for(int j=0;j<24;j++) hv[j] = fmaf(hk1, w1[j], hv[j]);
    }
    float l0=bc2[0], l1=bc2[1];
#pragma unroll
    for(int j=0;j<24;j++){
      float a = fmaxf(hv[j],0.f);
      l0 = fmaf(a, Wc2[2*j],   l0);
      l1 = fmaf(a, Wc2[2*j+1], l1);
    }
    reinterpret_cast<float2*>(out)[n] = make_float2(l0,l1);
  }
}

static inline size_t al256(size_t x){ return (x+255)&~(size_t)255; }

extern "C" void kernel_launch(void* const* d_in, const int* in_sizes, int n_in,
                              void* d_out, int out_size, void* d_ws, size_t ws_size,
                              hipStream_t stream){
  const float* x_seq=(const float*)d_in[0];
  const int*   ei   =(const int*)d_in[1];
  const float* ew   =(const float*)d_in[2];
  const float* W0=(const float*)d_in[3];  const float* b0=(const float*)d_in[4];
  const float* g0=(const float*)d_in[5];  const float* be0=(const float*)d_in[6];
  const float* W1=(const float*)d_in[7];  const float* b1=(const float*)d_in[8];
  const float* g1=(const float*)d_in[9];  const float* be1=(const float*)d_in[10];
  const float* Wih=(const float*)d_in[11];const float* Whh=(const float*)d_in[12];
  const float* bih=(const float*)d_in[13];const float* bhh=(const float*)d_in[14];
  const float* Wc1=(const float*)d_in[15];const float* bc1=(const float*)d_in[16];
  const float* Wc2=(const float*)d_in[17];const float* bc2=(const float*)d_in[18];
  float* outp=(float*)d_out;

  char* p=(char*)d_ws; size_t off=0;
  auto alloc=[&](size_t bytes)->void*{ void* r=p+off; off=al256(off+bytes); return r; };
  float* dis    =(float*)alloc((size_t)NN*4);
  int*   cnt    =(int*)  alloc((size_t)NN*4);
  int*   offs   =(int*)  alloc((size_t)(NN+1)*4);
  int*   bsum   =(int*)  alloc((size_t)NB*4);
  int*   bpre   =(int*)  alloc((size_t)NB*4);
  int*   pos    =(int*)  alloc((size_t)NE*4);
  int2*  csr    =(int2*) alloc((size_t)NE*8);
  unsigned* W2  =(unsigned*)alloc((size_t)12*24*24*4);
  unsigned* A   =(unsigned*)alloc((size_t)NN*AW*4 + 1024);  // bf16 rows, 640B line-aligned
  float* h1     =(float*)alloc((size_t)NN*TT*HID*4);
  unsigned* h2p =(unsigned*)alloc((size_t)NN*144*4);        // packed fp16 h2 [n][t][24]

  const int GN=(NN+255)/256, GE=(NE+255)/256;
  const int GMM=(NN+63)/64;              // 64 nodes/block
  const int GAGG=(NN*64+255)/256;        // 1 wave/node
  const int GGRU=(NN+63)/64;             // 64 nodes/block, 12 waves

  k_setup  <<<GN,256,0,stream>>>(cnt,Wih,Whh,W2);
  k_cnt    <<<GE,256,0,stream>>>(ei,cnt,pos);
  k_partA  <<<NB,256,0,stream>>>(cnt,bsum);
  k_midB   <<<1,256,0,stream>>>(bsum,bpre,offs);
  k_offsC  <<<NB,256,0,stream>>>(cnt,bpre,offs);
  k_scatter<<<GE,256,0,stream>>>(ei,ew,offs,pos,csr);
  k_deg    <<<GN,256,0,stream>>>(csr,offs,dis);
  k_normE  <<<GE,256,0,stream>>>(csr,dis);

  // layer 0 -> h1 (fp32, needed as mm1 input + residual)
  k_mm0<<<GMM,256,0,stream>>>(x_seq, W0, A);
  k_agg<<<GAGG,256,0,stream>>>(A,b0,g0,be0,nullptr,h1,nullptr,offs,csr,dis);
  // layer 1 -> h2 packed fp16 (feeds GRU directly; resid = h1)
  k_mm1<<<GMM,256,0,stream>>>(h1, W1, A);
  k_agg<<<GAGG,256,0,stream>>>(A,b1,g1,be1,h1,nullptr,h2p,offs,csr,dis);
  // fused GRU v5 (node-major LDS, pure-SMEM k-loops) + classifier
  k_gruF5<<<GGRU,768,0,stream>>>(h2p, W2, bih,bhh, Wc1,bc1,Wc2,bc2, outp);
}